// Round 12
// baseline (210.646 us; speedup 1.0000x reference)
//
#include <hip/hip_runtime.h>
#include <math.h>

// Problem constants
#define NG   12
#define NH   8
#define CIN  64
#define CQK  32
#define CVAL 32
#define COUT 64
#define NB   2
#define NN   512
#define NROWS (NB * NN)     // 1024
#define GHH  (NG * NH)      // 96 heads
#define DIN  (NG * CIN)     // 768
#define DQK  (GHH * CQK)    // 3072
#define DOUT (NG * COUT)    // 768

typedef __attribute__((ext_vector_type(8))) short bf16x8;
typedef __attribute__((ext_vector_type(4))) float f32x4;
typedef unsigned short ushort_t;

#define SZU ((size_t)NROWS * DQK)   // 3145728 elements per fp32 region

__device__ __forceinline__ ushort_t bf16_rne(float v) {
    unsigned u = __float_as_uint(v);
    return (ushort_t)((u + 0x7fffu + ((u >> 16) & 1u)) >> 16);
}

// ---------------------------------------------------------------------------
// Fused prep (block-range dispatch):
// blocks [0,384):   X split + swizzle into A-frag order
// blocks [384,672): Wq/Wk/Wv split + swizzle into B-frag order
// blocks [672,768): Wo split + swizzle -> WOr planes staged in d_out
// ---------------------------------------------------------------------------
__global__ __launch_bounds__(256) void prep_kernel(
    const float* __restrict__ feat,
    const float* __restrict__ Wq, const float* __restrict__ Wk,
    const float* __restrict__ Wv, const float* __restrict__ Wo,
    ushort_t* __restrict__ Xrh, ushort_t* __restrict__ Xrl,
    ushort_t* __restrict__ Wqh, ushort_t* __restrict__ Wql,
    ushort_t* __restrict__ WOrh, ushort_t* __restrict__ WOrl)
{
    const int bb = blockIdx.x;
    if (bb < 384) {
        const int t  = bb * 256 + threadIdx.x;   // [0, 98304)
        const int mr  = t & 15;
        const int u   = t >> 4;
        const int kc  = u % 96;
        const int m16 = u / 96;
        const float* src = feat + (size_t)(m16 * 16 + mr) * DIN + kc * 8;
        float v[8];
        *(float4*)v       = *(const float4*)src;
        *(float4*)(v + 4) = *(const float4*)(src + 4);
        ushort_t h8[8] __attribute__((aligned(16)));
        ushort_t l8[8] __attribute__((aligned(16)));
        #pragma unroll
        for (int j = 0; j < 8; ++j) {
            ushort_t hb = bf16_rne(v[j]);
            float hf = __uint_as_float(((unsigned)hb) << 16);
            h8[j] = hb;
            l8[j] = bf16_rne(v[j] - hf);
        }
        const size_t dst = ((size_t)m16 * 96 + kc) * 128 + mr * 8;
        *(uint4*)(Xrh + dst) = *(const uint4*)h8;
        *(uint4*)(Xrl + dst) = *(const uint4*)l8;
    } else if (bb < 672) {
        const int zz = (bb - 384) / 96;
        const float* W = (zz == 0) ? Wq : (zz == 1) ? Wk : Wv;
        ushort_t* hi = Wqh + (size_t)zz * 196608;
        ushort_t* lo = Wql + (size_t)zz * 196608;
        const int t  = ((bb - 384) % 96) * 256 + threadIdx.x;   // [0, 24576)
        const int kc = t & 7;
        const int o  = (t >> 3) & 255;
        const int gp = t >> 11;
        const float* src = W + ((size_t)(gp * 256 + o)) * 64 + kc * 8;
        float v[8];
        *(float4*)v       = *(const float4*)src;
        *(float4*)(v + 4) = *(const float4*)(src + 4);
        ushort_t h8[8] __attribute__((aligned(16)));
        ushort_t l8[8] __attribute__((aligned(16)));
        #pragma unroll
        for (int j = 0; j < 8; ++j) {
            ushort_t hb = bf16_rne(v[j]);
            float hf = __uint_as_float(((unsigned)hb) << 16);
            h8[j] = hb;
            l8[j] = bf16_rne(v[j] - hf);
        }
        const size_t dst = ((size_t)(gp * 16 + (o >> 4)) * 8 + kc) * 128 + (o & 15) * 8;
        *(uint4*)(hi + dst) = *(const uint4*)h8;
        *(uint4*)(lo + dst) = *(const uint4*)l8;
    } else {
        const int t  = (bb - 672) * 256 + threadIdx.x;   // [0, 24576)
        const int kc = t & 31;
        const int o  = (t >> 5) & 63;
        const int gp = t >> 11;
        const float* src = Wo + ((size_t)(gp * 64 + o)) * 256 + kc * 8;
        float v[8];
        *(float4*)v       = *(const float4*)src;
        *(float4*)(v + 4) = *(const float4*)(src + 4);
        ushort_t h8[8] __attribute__((aligned(16)));
        ushort_t l8[8] __attribute__((aligned(16)));
        #pragma unroll
        for (int j = 0; j < 8; ++j) {
            ushort_t hb = bf16_rne(v[j]);
            float hf = __uint_as_float(((unsigned)hb) << 16);
            h8[j] = hb;
            l8[j] = bf16_rne(v[j] - hf);
        }
        const size_t dst = ((size_t)(gp * 4 + (o >> 4)) * 32 + kc) * 128 + (o & 15) * 8;
        *(uint4*)(WOrh + dst) = *(const uint4*)h8;
        *(uint4*)(WOrl + dst) = *(const uint4*)l8;
    }
}

// ---------------------------------------------------------------------------
// Kernel 1: block-circulant QKV projection — EXACT round-0 body, DO NOT TOUCH
// (9 failed variants: ILP/TLP/locality/fusion/tiling all regress).
// ---------------------------------------------------------------------------
__global__ __launch_bounds__(256, 1) void qkv_mfma_kernel(
    const ushort_t* __restrict__ Xrh, const ushort_t* __restrict__ Xrl,
    const ushort_t* __restrict__ Wrh, const ushort_t* __restrict__ Wrl,
    float* __restrict__ qo, float* __restrict__ ko, float* __restrict__ vo)
{
    const int z = blockIdx.z;
    float* __restrict__ out = (z == 0) ? qo : (z == 1) ? ko : vo;
    const ushort_t* Wh = Wrh + (size_t)z * 196608;
    const ushort_t* Wl = Wrl + (size_t)z * 196608;
    const int m0 = blockIdx.y * 128;
    const int c0 = blockIdx.x * 128;
    const int hg = c0 >> 8;
    const int o0 = c0 & 255;
    const int tid  = threadIdx.x;
    const int lane = tid & 63;
    const int w    = tid >> 6;
    const int wm   = (w >> 1) * 64;
    const int wn   = (w & 1) * 64;
    const int lm   = lane & 15;
    const int lq   = lane >> 4;
    const int tA0  = (m0 + wm) >> 4;
    const int ct0  = (o0 + wn) >> 4;

    f32x4 acc[4][4];
    #pragma unroll
    for (int i = 0; i < 4; ++i)
        #pragma unroll
        for (int j = 0; j < 4; ++j) acc[i][j] = (f32x4)(0.0f);

    for (int ks = 0; ks < 24; ++ks) {
        const int g = ks >> 1;
        int gp = g - hg; if (gp < 0) gp += NG;
        bf16x8 ah[4], al[4], bh[4], bl[4];
        #pragma unroll
        for (int mt = 0; mt < 4; ++mt) {
            const size_t aoff = ((size_t)(tA0 + mt) * 96 + ks * 4 + lq) * 128 + lm * 8;
            ah[mt] = *(const bf16x8*)(Xrh + aoff);
            al[mt] = *(const bf16x8*)(Xrl + aoff);
        }
        const size_t bbase = ((size_t)(gp * 16 + ct0) * 8 + (ks & 1) * 4 + lq) * 128 + lm * 8;
        #pragma unroll
        for (int nt = 0; nt < 4; ++nt) {
            bh[nt] = *(const bf16x8*)(Wh + bbase + nt * 1024);
            bl[nt] = *(const bf16x8*)(Wl + bbase + nt * 1024);
        }
        #pragma unroll
        for (int mt = 0; mt < 4; ++mt)
            #pragma unroll
            for (int nt = 0; nt < 4; ++nt) {
                acc[mt][nt] = __builtin_amdgcn_mfma_f32_16x16x32_bf16(ah[mt], bh[nt], acc[mt][nt], 0, 0, 0);
                acc[mt][nt] = __builtin_amdgcn_mfma_f32_16x16x32_bf16(ah[mt], bl[nt], acc[mt][nt], 0, 0, 0);
                acc[mt][nt] = __builtin_amdgcn_mfma_f32_16x16x32_bf16(al[mt], bh[nt], acc[mt][nt], 0, 0, 0);
            }
    }
    #pragma unroll
    for (int mt = 0; mt < 4; ++mt)
        #pragma unroll
        for (int r = 0; r < 4; ++r) {
            float* dst = out + (size_t)(m0 + wm + mt * 16 + lq * 4 + r) * DQK + c0 + wn + lm;
            #pragma unroll
            for (int nt = 0; nt < 4; ++nt) dst[nt * 16] = acc[mt][nt][r];
        }
}

// ---------------------------------------------------------------------------
// Kernel 2: K-ONLY RMSNorm + fused ropes -> split-bf16 Kr B-fragment planes.
// ---------------------------------------------------------------------------
__global__ __launch_bounds__(256) void norm_rope_kernel(
    const float* __restrict__ kin,
    ushort_t* __restrict__ krh, ushort_t* __restrict__ krl,
    const float* __restrict__ coords,
    const int* __restrict__ seq,
    const float* __restrict__ kw,
    const float* __restrict__ pf)
{
    const int hid = blockIdx.x * 256 + threadIdx.x;
    const int gh = hid % GHH;
    const int bn = hid / GHH;
    const int g = gh >> 3;
    const int h = gh & 7;
    const float* kp = kin + (size_t)hid * CQK;
    float xk[CQK];
    #pragma unroll
    for (int u = 0; u < 8; ++u) *(float4*)(xk + 4 * u) = *(const float4*)(kp + 4 * u);

    float sk = 0.f;
    #pragma unroll
    for (int c = 0; c < CQK; ++c) sk = fmaf(xk[c], xk[c], sk);
    const float eps = 1.1920928955078125e-07f;
    const float invk = rsqrtf(sk * (1.f / CQK) + eps);
    #pragma unroll
    for (int c = 0; c < CQK; ++c) xk[c] *= invk * kw[c];

    const float pos = (float)seq[bn];
    const float cx = coords[bn * 3 + 0], cy = coords[bn * 3 + 1], cz = coords[bn * 3 + 2];
    float sg, cg;
    sincosf((float)g * 0.5235987755982988f, &sg, &cg);
    const float u0 = cg * cx + sg * cy;
    const float u1 = cg * cy - sg * cx;
    const float u2 = cz;

    #pragma unroll
    for (int f = 0; f < 16; ++f) {
        const float invf = exp2f(-(float)f * 0.8304820237218405f);
        const float* fr = pf + ((size_t)h * 16 + f) * 3;
        const float ang = fmaf(pos, invf, u0 * fr[0] + u1 * fr[1] + u2 * fr[2]);
        float sn, cs;
        sincosf(ang, &sn, &cs);
        float b1 = xk[2 * f], b2 = xk[2 * f + 1];
        xk[2 * f]     = b1 * cs - b2 * sn;
        xk[2 * f + 1] = b1 * sn + b2 * cs;
    }

    const int b = bn >> 9, n = bn & 511;
    const size_t kbase = (((size_t)(b * GHH + gh) * 32 + (n >> 4)) * 4) * 128 + (n & 15) * 8;
    #pragma unroll
    for (int kc = 0; kc < 4; ++kc) {
        ushort_t h8[8] __attribute__((aligned(16)));
        ushort_t l8[8] __attribute__((aligned(16)));
        #pragma unroll
        for (int j = 0; j < 8; ++j) {
            const float x = xk[kc * 8 + j];
            const ushort_t hb = bf16_rne(x);
            h8[j] = hb;
            l8[j] = bf16_rne(x - __uint_as_float(((unsigned)hb) << 16));
        }
        *(uint4*)(krh + kbase + kc * 128) = *(const uint4*)h8;
        *(uint4*)(krl + kbase + kc * 128) = *(const uint4*)l8;
    }
}

// ---------------------------------------------------------------------------
// Kernel 2b: V pack — fp32 V -> split-bf16 V^T B-fragment planes.
// ---------------------------------------------------------------------------
__global__ __launch_bounds__(256) void vpack_kernel(
    const float* __restrict__ v,
    ushort_t* __restrict__ vrh, ushort_t* __restrict__ vrl)
{
    const int t  = blockIdx.x * 256 + threadIdx.x;   // [0, 393216)
    const int vd = t & 31;
    const int kc = (t >> 5) & 63;
    const int bg = t >> 11;                          // [0, 192)
    const int b  = (bg >= GHH) ? 1 : 0;
    const int gh = bg - b * GHH;
    const float* src = v + (size_t)(b * 512 + kc * 8) * DQK + gh * 32 + vd;
    ushort_t h8[8] __attribute__((aligned(16)));
    ushort_t l8[8] __attribute__((aligned(16)));
    #pragma unroll
    for (int j = 0; j < 8; ++j) {
        const float x = src[j * DQK];
        const ushort_t hb = bf16_rne(x);
        h8[j] = hb;
        l8[j] = bf16_rne(x - __uint_as_float(((unsigned)hb) << 16));
    }
    const size_t dst = ((size_t)(bg * 2 + (vd >> 4)) * 64 + kc) * 128 + (vd & 15) * 8;
    *(uint4*)(vrh + dst) = *(const uint4*)h8;
    *(uint4*)(vrl + dst) = *(const uint4*)l8;
}

// ---------------------------------------------------------------------------
// Kernel 3: MFMA flash attention, NO-MAX softmax; q norm+rope in prologue;
// AO epilogue via dead-Ps LDS repack (round-11, +1 µs win).
// ---------------------------------------------------------------------------
__global__ __launch_bounds__(256, 1) void attn_mfma_kernel(
    const float* __restrict__ q,
    const ushort_t* __restrict__ krh, const ushort_t* __restrict__ krl,
    const ushort_t* __restrict__ vrh, const ushort_t* __restrict__ vrl,
    ushort_t* __restrict__ aoh,     // A-frag order [m>>4][384][16][8]
    ushort_t* __restrict__ aol,
    const float* __restrict__ coords, const int* __restrict__ seq,
    const float* __restrict__ qw, const float* __restrict__ pf)
{
    __shared__ __attribute__((aligned(16))) ushort_t Ps[128][72];

    const int gh    = blockIdx.x;
    const int chunk = blockIdx.y;
    const int b     = blockIdx.z;
    const size_t headoff = (size_t)b * NN * DQK + (size_t)gh * CQK;
    const size_t kvhead = (size_t)(b * GHH + gh) * 16384;
    const int tid  = threadIdx.x;
    const int lane = tid & 63;
    const int w    = tid >> 6;
    const int lm   = lane & 15;
    const int lq   = lane >> 4;       // quad
    const int qloc = w * 32;          // wave's local q-row base (0..96)

    const int hh = gh & 7;
    float sg, cg;
    sincosf((float)(gh >> 3) * 0.5235987755982988f, &sg, &cg);
    float invf[4], fr0[4], fr1[4], fr2[4];
    #pragma unroll
    for (int u = 0; u < 4; ++u) {
        const int f = lq * 4 + u;
        invf[u] = exp2f(-(float)f * 0.8304820237218405f);
        const float* fr = pf + ((size_t)hh * 16 + f) * 3;
        fr0[u] = fr[0]; fr1[u] = fr[1]; fr2[u] = fr[2];
    }
    float qwv[8];
    *(float4*)qwv       = *(const float4*)(qw + lq * 8);
    *(float4*)(qwv + 4) = *(const float4*)(qw + lq * 8 + 4);

    const float scale = 0.17677669529663687f;  // 1/sqrt(32)
    const float eps = 1.1920928955078125e-07f;
    bf16x8 qh[2], ql[2];
    #pragma unroll
    for (int mt = 0; mt < 2; ++mt) {
        const int row = chunk * 128 + qloc + mt * 16 + lm;
        const int bn  = b * NN + row;
        const float* qp = q + headoff + (size_t)row * DQK + lq * 8;
        float4 t0 = *(const float4*)qp;
        float4 t1 = *(const float4*)(qp + 4);
        float vals[8] = {t0.x, t0.y, t0.z, t0.w, t1.x, t1.y, t1.z, t1.w};

        float ss = 0.f;
        #pragma unroll
        for (int j = 0; j < 8; ++j) ss = fmaf(vals[j], vals[j], ss);
        ss += __shfl_xor(ss, 16, 64);
        ss += __shfl_xor(ss, 32, 64);
        const float inv = rsqrtf(ss * (1.0f / 32.0f) + eps);

        const float pos = (float)seq[bn];
        const float cx = coords[bn * 3], cy = coords[bn * 3 + 1], cz = coords[bn * 3 + 2];
        const float u0 = cg * cx + sg * cy;
        const float u1 = cg * cy - sg * cx;
        const float u2 = cz;

        float o8[8];
        #pragma unroll
        for (int u = 0; u < 4; ++u) {
            const float ang = fmaf(pos, invf[u], u0 * fr0[u] + u1 * fr1[u] + u2 * fr2[u]);
            float sn, cs;
            sincosf(ang, &sn, &cs);
            const float x1 = vals[2 * u]     * inv * qwv[2 * u];
            const float x2 = vals[2 * u + 1] * inv * qwv[2 * u + 1];
            o8[2 * u]     = x1 * cs - x2 * sn;
            o8[2 * u + 1] = x1 * sn + x2 * cs;
        }

        short h8[8], l8[8];
        #pragma unroll
        for (int j = 0; j < 8; ++j) {
            float x = o8[j] * scale;
            ushort_t hb = bf16_rne(x);
            float hf = __uint_as_float(((unsigned)hb) << 16);
            h8[j] = (short)hb;
            l8[j] = (short)bf16_rne(x - hf);
        }
        qh[mt] = *(bf16x8*)h8;
        ql[mt] = *(bf16x8*)l8;
    }

    float lacc[2][4];
    f32x4 o[2][2];
    #pragma unroll
    for (int mt = 0; mt < 2; ++mt) {
        #pragma unroll
        for (int r = 0; r < 4; ++r) lacc[mt][r] = 0.f;
        o[mt][0] = (f32x4)(0.0f); o[mt][1] = (f32x4)(0.0f);
    }

    for (int j0 = 0; j0 < NN; j0 += 64) {
        f32x4 sf[2][4];
        #pragma unroll
        for (int nt = 0; nt < 4; ++nt) {
            const size_t kb = kvhead + ((size_t)(((j0 >> 4) + nt) * 4 + lq)) * 128 + lm * 8;
            bf16x8 bh = *(const bf16x8*)(krh + kb);
            bf16x8 bl = *(const bf16x8*)(krl + kb);
            #pragma unroll
            for (int mt = 0; mt < 2; ++mt) {
                f32x4 s = (f32x4)(0.0f);
                s = __builtin_amdgcn_mfma_f32_16x16x32_bf16(qh[mt], bh, s, 0, 0, 0);
                s = __builtin_amdgcn_mfma_f32_16x16x32_bf16(qh[mt], bl, s, 0, 0, 0);
                s = __builtin_amdgcn_mfma_f32_16x16x32_bf16(ql[mt], bh, s, 0, 0, 0);
                sf[mt][nt] = s;
            }
        }

        #pragma unroll
        for (int mt = 0; mt < 2; ++mt)
            #pragma unroll
            for (int nt = 0; nt < 4; ++nt)
                #pragma unroll
                for (int r = 0; r < 4; ++r) {
                    const float p = __expf(sf[mt][nt][r]);
                    lacc[mt][r] += p;
                    Ps[qloc + mt * 16 + lq * 4 + r][nt * 16 + lm] = bf16_rne(p);
                }

        #pragma unroll
        for (int kt = 0; kt < 2; ++kt) {
            bf16x8 pa[2];
            #pragma unroll
            for (int mt = 0; mt < 2; ++mt)
                pa[mt] = *(const bf16x8*)&Ps[qloc + mt * 16 + lm][kt * 32 + lq * 8];
            #pragma unroll
            for (int vt = 0; vt < 2; ++vt) {
                const size_t vb = kvhead + ((size_t)(vt * 64 + (j0 >> 3) + kt * 4 + lq) * 16 + lm) * 8;
                bf16x8 bvh = *(const bf16x8*)(vrh + vb);
                bf16x8 bvl = *(const bf16x8*)(vrl + vb);
                #pragma unroll
                for (int mt = 0; mt < 2; ++mt) {
                    o[mt][vt] = __builtin_amdgcn_mfma_f32_16x16x32_bf16(pa[mt], bvh, o[mt][vt], 0, 0, 0);
                    o[mt][vt] = __builtin_amdgcn_mfma_f32_16x16x32_bf16(pa[mt], bvl, o[mt][vt], 0, 0, 0);
                }
            }
        }
    }

    #pragma unroll
    for (int mt = 0; mt < 2; ++mt)
        #pragma unroll
        for (int r = 0; r < 4; ++r) {
            float t = lacc[mt][r];
            t += __shfl_xor(t, 1, 64);
            t += __shfl_xor(t, 2, 64);
            t += __shfl_xor(t, 4, 64);
            t += __shfl_xor(t, 8, 64);
            lacc[mt][r] = 1.f / t;
        }

    // ---- epilogue: normalize + pack into dead Ps (u32 = hi<<16|lo), then
    //      drain as coalesced uint4 stores in A-FRAGMENT order ----
    __syncthreads();                               // all waves done with Ps
    unsigned int* bufU = (unsigned int*)&Ps[0][0]; // 4096 u32 = 16 KB
    const int mtbase0 = (b * 512 + chunk * 128) >> 4;
    const int kcl0 = lm >> 3;                      // 0/1 (x1 goes to +2)
    #pragma unroll
    for (int mt = 0; mt < 2; ++mt) {
        const int lmt = w * 2 + mt;                // local mtile 0..7
        #pragma unroll
        for (int r = 0; r < 4; ++r) {
            const int i = (lq * 4 + r) * 8 + (lm & 7);
            const float x0 = o[mt][0][r] * lacc[mt][r];
            const float x1 = o[mt][1][r] * lacc[mt][r];
            const ushort_t h0 = bf16_rne(x0);
            const ushort_t h1 = bf16_rne(x1);
            const ushort_t l0 = bf16_rne(x0 - __uint_as_float(((unsigned)h0) << 16));
            const ushort_t l1 = bf16_rne(x1 - __uint_as_float(((unsigned)h1) << 16));
            bufU[(lmt * 4 + kcl0) * 128 + i]       = (((unsigned)h0) << 16) | (unsigned)l0;
            bufU[(lmt * 4 + kcl0 + 2) * 128 + i]   = (((unsigned)h1) << 16) | (unsigned)l1;
        }
    }
    __syncthreads();
    // drain: 4096 u32 -> 512 chunks of 8 elems; 256 threads x 2 chunks
    #pragma unroll
    for (int it = 0; it < 2; ++it) {
        const int cid = it * 256 + tid;            // [0, 512)
        const int L   = cid * 8;                   // u32 index
        const int lmt = L >> 9;                    // /512
        const int kcl = (L >> 7) & 3;
        const int i0  = L & 127;
        const unsigned int* p = bufU + L;
        const uint4 a = *(const uint4*)p;
        const uint4 c = *(const uint4*)(p + 4);
        uint4 hi4, lo4;
        hi4.x = (a.x >> 16) | (a.y & 0xffff0000u);
        hi4.y = (a.z >> 16) | (a.w & 0xffff0000u);
        hi4.z = (c.x >> 16) | (c.y & 0xffff0000u);
        hi4.w = (c.z >> 16) | (c.w & 0xffff0000u);
        lo4.x = (a.x & 0xffffu) | (a.y << 16);
        lo4.y = (a.z & 0xffffu) | (a.w << 16);
        lo4.z = (c.x & 0xffffu) | (c.y << 16);
        lo4.w = (c.z & 0xffffu) | (c.w << 16);
        const size_t gaddr = ((size_t)(mtbase0 + lmt) * 384 + (gh * 4 + kcl)) * 128 + i0;
        *(uint4*)(aoh + gaddr) = hi4;
        *(uint4*)(aol + gaddr) = lo4;
    }
}

// ---------------------------------------------------------------------------
// Kernel 4: output projection, split-bf16 MFMA, split-K=4 (was 8): halves
// the fp32 partial traffic (24->12 MB write, 27->15 MB reduce) at unchanged
// per-ks instruction mix; 384 blocks = 1.5/CU.
// ---------------------------------------------------------------------------
__global__ __launch_bounds__(256, 1) void oproj_mfma_kernel(
    const ushort_t* __restrict__ Arh, const ushort_t* __restrict__ Arl,
    const ushort_t* __restrict__ Worh, const ushort_t* __restrict__ Worl,
    float* __restrict__ part)                                 // [4][1024][768]
{
    const int h  = blockIdx.x;
    const int m0 = blockIdx.y * 128;
    const int kz = blockIdx.z;              // [0,4)
    const int tid  = threadIdx.x;
    const int lane = tid & 63;
    const int w    = tid >> 6;
    const int wm   = (w >> 1) * 64;
    const int wn   = (w & 1) * 32;
    const int lm   = lane & 15;
    const int lq   = lane >> 4;
    const int tA0  = (m0 + wm) >> 4;
    const int ctb  = wn >> 4;               // 0 or 2

    f32x4 acc[4][2];
    #pragma unroll
    for (int i = 0; i < 4; ++i) { acc[i][0] = (f32x4)(0.0f); acc[i][1] = (f32x4)(0.0f); }

    for (int ks = 0; ks < 24; ++ks) {
        const int k0 = kz * 768 + ks * 32;
        const int g  = k0 >> 8;
        int gp = g - h; if (gp < 0) gp += NG;
        const int kcA = kz * 96 + ks * 4 + lq;
        const int kcB = ((k0 & 255) >> 3) + lq;
        bf16x8 ah[4], al[4], bh[2], bl[2];
        #pragma unroll
        for (int mt = 0; mt < 4; ++mt) {
            const size_t aoff = ((size_t)(tA0 + mt) * 384 + kcA) * 128 + lm * 8;
            ah[mt] = *(const bf16x8*)(Arh + aoff);
            al[mt] = *(const bf16x8*)(Arl + aoff);
        }
        const size_t bbase = ((size_t)(gp * 4 + ctb) * 32 + kcB) * 128 + lm * 8;
        #pragma unroll
        for (int nt = 0; nt < 2; ++nt) {
            bh[nt] = *(const bf16x8*)(Worh + bbase + nt * 4096);
            bl[nt] = *(const bf16x8*)(Worl + bbase + nt * 4096);
        }
        #pragma unroll
        for (int mt = 0; mt < 4; ++mt)
            #pragma unroll
            for (int nt = 0; nt < 2; ++nt) {
                acc[mt][nt] = __builtin_amdgcn_mfma_f32_16x16x32_bf16(ah[mt], bh[nt], acc[mt][nt], 0, 0, 0);
                acc[mt][nt] = __builtin_amdgcn_mfma_f32_16x16x32_bf16(ah[mt], bl[nt], acc[mt][nt], 0, 0, 0);
                acc[mt][nt] = __builtin_amdgcn_mfma_f32_16x16x32_bf16(al[mt], bh[nt], acc[mt][nt], 0, 0, 0);
            }
    }
    float* dst0 = part + (size_t)kz * (NROWS * DOUT);
    #pragma unroll
    for (int mt = 0; mt < 4; ++mt)
        #pragma unroll
        for (int r = 0; r < 4; ++r) {
            float* dst = dst0 + (size_t)(m0 + wm + mt * 16 + lq * 4 + r) * DOUT + h * 64 + wn + lm;
            dst[0]  = acc[mt][0][r];
            dst[16] = acc[mt][1][r];
        }
}

__global__ __launch_bounds__(256) void reduce4_kernel(
    const float* __restrict__ part, float* __restrict__ out)
{
    const int i = blockIdx.x * 256 + threadIdx.x;   // over 196608 float4s
    const float4* p = (const float4*)part;
    const int s = NROWS * DOUT / 4;                 // 196608
    float4 r = p[i];
    #pragma unroll
    for (int j = 1; j < 4; ++j) {
        float4 t = p[i + j * s];
        r.x += t.x; r.y += t.y; r.z += t.z; r.w += t.w;
    }
    ((float4*)out)[i] = r;
}

// ---------------------------------------------------------------------------
extern "C" void kernel_launch(void* const* d_in, const int* in_sizes, int n_in,
                              void* d_out, int out_size, void* d_ws, size_t ws_size,
                              hipStream_t stream)
{
    const float* feat   = (const float*)d_in[0];
    const float* coords = (const float*)d_in[1];
    const float* Wq     = (const float*)d_in[2];
    const float* Wk     = (const float*)d_in[3];
    const float* Wv     = (const float*)d_in[4];
    const float* Wo     = (const float*)d_in[5];
    const float* qw     = (const float*)d_in[6];
    const float* kw     = (const float*)d_in[7];
    const float* pf     = (const float*)d_in[8];
    const int*   seq    = (const int*)d_in[9];

    // regions (SZU floats each): qreg | kreg | vreg | aoreg
    float* qreg  = (float*)d_ws;
    float* kreg  = qreg + SZU;
    float* vreg  = kreg + SZU;
    float* aoreg = vreg + SZU;

    // phase 1: Xr + Wqkv planes in aoreg; WOr planes staged in d_out
    ushort_t* Xrh = (ushort_t*)aoreg;
    ushort_t* Xrl = Xrh + (size_t)NROWS * DIN;               // 786432 each
    ushort_t* Wqh = Xrl + (size_t)NROWS * DIN;
    ushort_t* Wql = Wqh + (size_t)3 * 196608;
    ushort_t* WOrh = (ushort_t*)d_out;
    ushort_t* WOrl = WOrh + (size_t)196608;
    // phase 2: qkv -> q,k,v fp32 in qreg,kreg,vreg.
    // norm_rope (k-only): k fp32 -> Kr planes -> aoreg (Xr/W dead).
    ushort_t* Krh = (ushort_t*)aoreg;
    ushort_t* Krl = Krh + SZU;
    // vpack: Vr planes -> kreg (k fp32 dead after norm_rope).
    ushort_t* Vrh = (ushort_t*)kreg;
    ushort_t* Vrl = Vrh + SZU;
    // attn: AOr planes -> vreg (v fp32 dead after vpack).
    ushort_t* AOrh = (ushort_t*)vreg;
    ushort_t* AOrl = AOrh + SZU;
    // after attn: partials [4][1024][768] = 12 MB -> qreg (q dead).
    float*    part = (float*)d_ws;

    prep_kernel<<<dim3(768), 256, 0, stream>>>(feat, Wq, Wk, Wv, Wo,
        Xrh, Xrl, Wqh, Wql, WOrh, WOrl);
    qkv_mfma_kernel<<<dim3(24, 8, 3), 256, 0, stream>>>(Xrh, Xrl, Wqh, Wql, qreg, kreg, vreg);
    norm_rope_kernel<<<dim3(384), 256, 0, stream>>>(kreg, Krh, Krl, coords, seq, kw, pf);
    vpack_kernel<<<dim3(1536), 256, 0, stream>>>(vreg, Vrh, Vrl);
    attn_mfma_kernel<<<dim3(96, 4, 2), 256, 0, stream>>>(qreg, Krh, Krl, Vrh, Vrl, AOrh, AOrl,
                                                         coords, seq, qw, pf);
    oproj_mfma_kernel<<<dim3(12, 8, 4), 256, 0, stream>>>(AOrh, AOrl, WOrh, WOrl, part);
    reduce4_kernel<<<dim3(768), 256, 0, stream>>>(part, (float*)d_out);
}

// Round 13
// 202.549 us; speedup vs baseline: 1.0400x; 1.0400x over previous
//
#include <hip/hip_runtime.h>
#include <math.h>

// Problem constants
#define NG   12
#define NH   8
#define CIN  64
#define CQK  32
#define CVAL 32
#define COUT 64
#define NB   2
#define NN   512
#define NROWS (NB * NN)     // 1024
#define GHH  (NG * NH)      // 96 heads
#define DIN  (NG * CIN)     // 768
#define DQK  (GHH * CQK)    // 3072
#define DOUT (NG * COUT)    // 768

typedef __attribute__((ext_vector_type(8))) short bf16x8;
typedef __attribute__((ext_vector_type(4))) float f32x4;
typedef unsigned short ushort_t;

#define SZU ((size_t)NROWS * DQK)   // 3145728 elements per fp32 region

__device__ __forceinline__ ushort_t bf16_rne(float v) {
    unsigned u = __float_as_uint(v);
    return (ushort_t)((u + 0x7fffu + ((u >> 16) & 1u)) >> 16);
}

// ---------------------------------------------------------------------------
// Fused prep (block-range dispatch):
// blocks [0,384):   X split + swizzle into A-frag order
// blocks [384,672): Wq/Wk/Wv split + swizzle into B-frag order
// blocks [672,768): Wo split + swizzle -> WOr planes staged in d_out
// ---------------------------------------------------------------------------
__global__ __launch_bounds__(256) void prep_kernel(
    const float* __restrict__ feat,
    const float* __restrict__ Wq, const float* __restrict__ Wk,
    const float* __restrict__ Wv, const float* __restrict__ Wo,
    ushort_t* __restrict__ Xrh, ushort_t* __restrict__ Xrl,
    ushort_t* __restrict__ Wqh, ushort_t* __restrict__ Wql,
    ushort_t* __restrict__ WOrh, ushort_t* __restrict__ WOrl)
{
    const int bb = blockIdx.x;
    if (bb < 384) {
        const int t  = bb * 256 + threadIdx.x;   // [0, 98304)
        const int mr  = t & 15;
        const int u   = t >> 4;
        const int kc  = u % 96;
        const int m16 = u / 96;
        const float* src = feat + (size_t)(m16 * 16 + mr) * DIN + kc * 8;
        float v[8];
        *(float4*)v       = *(const float4*)src;
        *(float4*)(v + 4) = *(const float4*)(src + 4);
        ushort_t h8[8] __attribute__((aligned(16)));
        ushort_t l8[8] __attribute__((aligned(16)));
        #pragma unroll
        for (int j = 0; j < 8; ++j) {
            ushort_t hb = bf16_rne(v[j]);
            float hf = __uint_as_float(((unsigned)hb) << 16);
            h8[j] = hb;
            l8[j] = bf16_rne(v[j] - hf);
        }
        const size_t dst = ((size_t)m16 * 96 + kc) * 128 + mr * 8;
        *(uint4*)(Xrh + dst) = *(const uint4*)h8;
        *(uint4*)(Xrl + dst) = *(const uint4*)l8;
    } else if (bb < 672) {
        const int zz = (bb - 384) / 96;
        const float* W = (zz == 0) ? Wq : (zz == 1) ? Wk : Wv;
        ushort_t* hi = Wqh + (size_t)zz * 196608;
        ushort_t* lo = Wql + (size_t)zz * 196608;
        const int t  = ((bb - 384) % 96) * 256 + threadIdx.x;   // [0, 24576)
        const int kc = t & 7;
        const int o  = (t >> 3) & 255;
        const int gp = t >> 11;
        const float* src = W + ((size_t)(gp * 256 + o)) * 64 + kc * 8;
        float v[8];
        *(float4*)v       = *(const float4*)src;
        *(float4*)(v + 4) = *(const float4*)(src + 4);
        ushort_t h8[8] __attribute__((aligned(16)));
        ushort_t l8[8] __attribute__((aligned(16)));
        #pragma unroll
        for (int j = 0; j < 8; ++j) {
            ushort_t hb = bf16_rne(v[j]);
            float hf = __uint_as_float(((unsigned)hb) << 16);
            h8[j] = hb;
            l8[j] = bf16_rne(v[j] - hf);
        }
        const size_t dst = ((size_t)(gp * 16 + (o >> 4)) * 8 + kc) * 128 + (o & 15) * 8;
        *(uint4*)(hi + dst) = *(const uint4*)h8;
        *(uint4*)(lo + dst) = *(const uint4*)l8;
    } else {
        const int t  = (bb - 672) * 256 + threadIdx.x;   // [0, 24576)
        const int kc = t & 31;
        const int o  = (t >> 5) & 63;
        const int gp = t >> 11;
        const float* src = Wo + ((size_t)(gp * 64 + o)) * 256 + kc * 8;
        float v[8];
        *(float4*)v       = *(const float4*)src;
        *(float4*)(v + 4) = *(const float4*)(src + 4);
        ushort_t h8[8] __attribute__((aligned(16)));
        ushort_t l8[8] __attribute__((aligned(16)));
        #pragma unroll
        for (int j = 0; j < 8; ++j) {
            ushort_t hb = bf16_rne(v[j]);
            float hf = __uint_as_float(((unsigned)hb) << 16);
            h8[j] = hb;
            l8[j] = bf16_rne(v[j] - hf);
        }
        const size_t dst = ((size_t)(gp * 4 + (o >> 4)) * 32 + kc) * 128 + (o & 15) * 8;
        *(uint4*)(WOrh + dst) = *(const uint4*)h8;
        *(uint4*)(WOrl + dst) = *(const uint4*)l8;
    }
}

// ---------------------------------------------------------------------------
// Kernel 1: block-circulant QKV projection — EXACT round-0 body, DO NOT TOUCH
// (10 failed variants: ILP/TLP/locality/fusion/tiling all regress).
// ---------------------------------------------------------------------------
__global__ __launch_bounds__(256, 1) void qkv_mfma_kernel(
    const ushort_t* __restrict__ Xrh, const ushort_t* __restrict__ Xrl,
    const ushort_t* __restrict__ Wrh, const ushort_t* __restrict__ Wrl,
    float* __restrict__ qo, float* __restrict__ ko, float* __restrict__ vo)
{
    const int z = blockIdx.z;
    float* __restrict__ out = (z == 0) ? qo : (z == 1) ? ko : vo;
    const ushort_t* Wh = Wrh + (size_t)z * 196608;
    const ushort_t* Wl = Wrl + (size_t)z * 196608;
    const int m0 = blockIdx.y * 128;
    const int c0 = blockIdx.x * 128;
    const int hg = c0 >> 8;
    const int o0 = c0 & 255;
    const int tid  = threadIdx.x;
    const int lane = tid & 63;
    const int w    = tid >> 6;
    const int wm   = (w >> 1) * 64;
    const int wn   = (w & 1) * 64;
    const int lm   = lane & 15;
    const int lq   = lane >> 4;
    const int tA0  = (m0 + wm) >> 4;
    const int ct0  = (o0 + wn) >> 4;

    f32x4 acc[4][4];
    #pragma unroll
    for (int i = 0; i < 4; ++i)
        #pragma unroll
        for (int j = 0; j < 4; ++j) acc[i][j] = (f32x4)(0.0f);

    for (int ks = 0; ks < 24; ++ks) {
        const int g = ks >> 1;
        int gp = g - hg; if (gp < 0) gp += NG;
        bf16x8 ah[4], al[4], bh[4], bl[4];
        #pragma unroll
        for (int mt = 0; mt < 4; ++mt) {
            const size_t aoff = ((size_t)(tA0 + mt) * 96 + ks * 4 + lq) * 128 + lm * 8;
            ah[mt] = *(const bf16x8*)(Xrh + aoff);
            al[mt] = *(const bf16x8*)(Xrl + aoff);
        }
        const size_t bbase = ((size_t)(gp * 16 + ct0) * 8 + (ks & 1) * 4 + lq) * 128 + lm * 8;
        #pragma unroll
        for (int nt = 0; nt < 4; ++nt) {
            bh[nt] = *(const bf16x8*)(Wh + bbase + nt * 1024);
            bl[nt] = *(const bf16x8*)(Wl + bbase + nt * 1024);
        }
        #pragma unroll
        for (int mt = 0; mt < 4; ++mt)
            #pragma unroll
            for (int nt = 0; nt < 4; ++nt) {
                acc[mt][nt] = __builtin_amdgcn_mfma_f32_16x16x32_bf16(ah[mt], bh[nt], acc[mt][nt], 0, 0, 0);
                acc[mt][nt] = __builtin_amdgcn_mfma_f32_16x16x32_bf16(ah[mt], bl[nt], acc[mt][nt], 0, 0, 0);
                acc[mt][nt] = __builtin_amdgcn_mfma_f32_16x16x32_bf16(al[mt], bh[nt], acc[mt][nt], 0, 0, 0);
            }
    }
    #pragma unroll
    for (int mt = 0; mt < 4; ++mt)
        #pragma unroll
        for (int r = 0; r < 4; ++r) {
            float* dst = out + (size_t)(m0 + wm + mt * 16 + lq * 4 + r) * DQK + c0 + wn + lm;
            #pragma unroll
            for (int nt = 0; nt < 4; ++nt) dst[nt * 16] = acc[mt][nt][r];
        }
}

// ---------------------------------------------------------------------------
// Kernel 2: K-ONLY RMSNorm + fused ropes -> split-bf16 Kr B-fragment planes.
// ---------------------------------------------------------------------------
__global__ __launch_bounds__(256) void norm_rope_kernel(
    const float* __restrict__ kin,
    ushort_t* __restrict__ krh, ushort_t* __restrict__ krl,
    const float* __restrict__ coords,
    const int* __restrict__ seq,
    const float* __restrict__ kw,
    const float* __restrict__ pf)
{
    const int hid = blockIdx.x * 256 + threadIdx.x;
    const int gh = hid % GHH;
    const int bn = hid / GHH;
    const int g = gh >> 3;
    const int h = gh & 7;
    const float* kp = kin + (size_t)hid * CQK;
    float xk[CQK];
    #pragma unroll
    for (int u = 0; u < 8; ++u) *(float4*)(xk + 4 * u) = *(const float4*)(kp + 4 * u);

    float sk = 0.f;
    #pragma unroll
    for (int c = 0; c < CQK; ++c) sk = fmaf(xk[c], xk[c], sk);
    const float eps = 1.1920928955078125e-07f;
    const float invk = rsqrtf(sk * (1.f / CQK) + eps);
    #pragma unroll
    for (int c = 0; c < CQK; ++c) xk[c] *= invk * kw[c];

    const float pos = (float)seq[bn];
    const float cx = coords[bn * 3 + 0], cy = coords[bn * 3 + 1], cz = coords[bn * 3 + 2];
    float sg, cg;
    sincosf((float)g * 0.5235987755982988f, &sg, &cg);
    const float u0 = cg * cx + sg * cy;
    const float u1 = cg * cy - sg * cx;
    const float u2 = cz;

    #pragma unroll
    for (int f = 0; f < 16; ++f) {
        const float invf = exp2f(-(float)f * 0.8304820237218405f);
        const float* fr = pf + ((size_t)h * 16 + f) * 3;
        const float ang = fmaf(pos, invf, u0 * fr[0] + u1 * fr[1] + u2 * fr[2]);
        float sn, cs;
        sincosf(ang, &sn, &cs);
        float b1 = xk[2 * f], b2 = xk[2 * f + 1];
        xk[2 * f]     = b1 * cs - b2 * sn;
        xk[2 * f + 1] = b1 * sn + b2 * cs;
    }

    const int b = bn >> 9, n = bn & 511;
    const size_t kbase = (((size_t)(b * GHH + gh) * 32 + (n >> 4)) * 4) * 128 + (n & 15) * 8;
    #pragma unroll
    for (int kc = 0; kc < 4; ++kc) {
        ushort_t h8[8] __attribute__((aligned(16)));
        ushort_t l8[8] __attribute__((aligned(16)));
        #pragma unroll
        for (int j = 0; j < 8; ++j) {
            const float x = xk[kc * 8 + j];
            const ushort_t hb = bf16_rne(x);
            h8[j] = hb;
            l8[j] = bf16_rne(x - __uint_as_float(((unsigned)hb) << 16));
        }
        *(uint4*)(krh + kbase + kc * 128) = *(const uint4*)h8;
        *(uint4*)(krl + kbase + kc * 128) = *(const uint4*)l8;
    }
}

// ---------------------------------------------------------------------------
// Kernel 2b: V pack — fp32 V -> split-bf16 V^T B-fragment planes.
// ---------------------------------------------------------------------------
__global__ __launch_bounds__(256) void vpack_kernel(
    const float* __restrict__ v,
    ushort_t* __restrict__ vrh, ushort_t* __restrict__ vrl)
{
    const int t  = blockIdx.x * 256 + threadIdx.x;   // [0, 393216)
    const int vd = t & 31;
    const int kc = (t >> 5) & 63;
    const int bg = t >> 11;                          // [0, 192)
    const int b  = (bg >= GHH) ? 1 : 0;
    const int gh = bg - b * GHH;
    const float* src = v + (size_t)(b * 512 + kc * 8) * DQK + gh * 32 + vd;
    ushort_t h8[8] __attribute__((aligned(16)));
    ushort_t l8[8] __attribute__((aligned(16)));
    #pragma unroll
    for (int j = 0; j < 8; ++j) {
        const float x = src[j * DQK];
        const ushort_t hb = bf16_rne(x);
        h8[j] = hb;
        l8[j] = bf16_rne(x - __uint_as_float(((unsigned)hb) << 16));
    }
    const size_t dst = ((size_t)(bg * 2 + (vd >> 4)) * 64 + kc) * 128 + (vd & 15) * 8;
    *(uint4*)(vrh + dst) = *(const uint4*)h8;
    *(uint4*)(vrl + dst) = *(const uint4*)l8;
}

// ---------------------------------------------------------------------------
// Kernel 3: MFMA flash attention, NO-MAX softmax; q norm+rope in prologue;
// AO epilogue via dead-Ps LDS repack (round-11, +1 µs win).
// ---------------------------------------------------------------------------
__global__ __launch_bounds__(256, 1) void attn_mfma_kernel(
    const float* __restrict__ q,
    const ushort_t* __restrict__ krh, const ushort_t* __restrict__ krl,
    const ushort_t* __restrict__ vrh, const ushort_t* __restrict__ vrl,
    ushort_t* __restrict__ aoh,     // A-frag order [m>>4][384][16][8]
    ushort_t* __restrict__ aol,
    const float* __restrict__ coords, const int* __restrict__ seq,
    const float* __restrict__ qw, const float* __restrict__ pf)
{
    __shared__ __attribute__((aligned(16))) ushort_t Ps[128][72];

    const int gh    = blockIdx.x;
    const int chunk = blockIdx.y;
    const int b     = blockIdx.z;
    const size_t headoff = (size_t)b * NN * DQK + (size_t)gh * CQK;
    const size_t kvhead = (size_t)(b * GHH + gh) * 16384;
    const int tid  = threadIdx.x;
    const int lane = tid & 63;
    const int w    = tid >> 6;
    const int lm   = lane & 15;
    const int lq   = lane >> 4;       // quad
    const int qloc = w * 32;          // wave's local q-row base (0..96)

    const int hh = gh & 7;
    float sg, cg;
    sincosf((float)(gh >> 3) * 0.5235987755982988f, &sg, &cg);
    float invf[4], fr0[4], fr1[4], fr2[4];
    #pragma unroll
    for (int u = 0; u < 4; ++u) {
        const int f = lq * 4 + u;
        invf[u] = exp2f(-(float)f * 0.8304820237218405f);
        const float* fr = pf + ((size_t)hh * 16 + f) * 3;
        fr0[u] = fr[0]; fr1[u] = fr[1]; fr2[u] = fr[2];
    }
    float qwv[8];
    *(float4*)qwv       = *(const float4*)(qw + lq * 8);
    *(float4*)(qwv + 4) = *(const float4*)(qw + lq * 8 + 4);

    const float scale = 0.17677669529663687f;  // 1/sqrt(32)
    const float eps = 1.1920928955078125e-07f;
    bf16x8 qh[2], ql[2];
    #pragma unroll
    for (int mt = 0; mt < 2; ++mt) {
        const int row = chunk * 128 + qloc + mt * 16 + lm;
        const int bn  = b * NN + row;
        const float* qp = q + headoff + (size_t)row * DQK + lq * 8;
        float4 t0 = *(const float4*)qp;
        float4 t1 = *(const float4*)(qp + 4);
        float vals[8] = {t0.x, t0.y, t0.z, t0.w, t1.x, t1.y, t1.z, t1.w};

        float ss = 0.f;
        #pragma unroll
        for (int j = 0; j < 8; ++j) ss = fmaf(vals[j], vals[j], ss);
        ss += __shfl_xor(ss, 16, 64);
        ss += __shfl_xor(ss, 32, 64);
        const float inv = rsqrtf(ss * (1.0f / 32.0f) + eps);

        const float pos = (float)seq[bn];
        const float cx = coords[bn * 3], cy = coords[bn * 3 + 1], cz = coords[bn * 3 + 2];
        const float u0 = cg * cx + sg * cy;
        const float u1 = cg * cy - sg * cx;
        const float u2 = cz;

        float o8[8];
        #pragma unroll
        for (int u = 0; u < 4; ++u) {
            const float ang = fmaf(pos, invf[u], u0 * fr0[u] + u1 * fr1[u] + u2 * fr2[u]);
            float sn, cs;
            sincosf(ang, &sn, &cs);
            const float x1 = vals[2 * u]     * inv * qwv[2 * u];
            const float x2 = vals[2 * u + 1] * inv * qwv[2 * u + 1];
            o8[2 * u]     = x1 * cs - x2 * sn;
            o8[2 * u + 1] = x1 * sn + x2 * cs;
        }

        short h8[8], l8[8];
        #pragma unroll
        for (int j = 0; j < 8; ++j) {
            float x = o8[j] * scale;
            ushort_t hb = bf16_rne(x);
            float hf = __uint_as_float(((unsigned)hb) << 16);
            h8[j] = (short)hb;
            l8[j] = (short)bf16_rne(x - hf);
        }
        qh[mt] = *(bf16x8*)h8;
        ql[mt] = *(bf16x8*)l8;
    }

    float lacc[2][4];
    f32x4 o[2][2];
    #pragma unroll
    for (int mt = 0; mt < 2; ++mt) {
        #pragma unroll
        for (int r = 0; r < 4; ++r) lacc[mt][r] = 0.f;
        o[mt][0] = (f32x4)(0.0f); o[mt][1] = (f32x4)(0.0f);
    }

    for (int j0 = 0; j0 < NN; j0 += 64) {
        f32x4 sf[2][4];
        #pragma unroll
        for (int nt = 0; nt < 4; ++nt) {
            const size_t kb = kvhead + ((size_t)(((j0 >> 4) + nt) * 4 + lq)) * 128 + lm * 8;
            bf16x8 bh = *(const bf16x8*)(krh + kb);
            bf16x8 bl = *(const bf16x8*)(krl + kb);
            #pragma unroll
            for (int mt = 0; mt < 2; ++mt) {
                f32x4 s = (f32x4)(0.0f);
                s = __builtin_amdgcn_mfma_f32_16x16x32_bf16(qh[mt], bh, s, 0, 0, 0);
                s = __builtin_amdgcn_mfma_f32_16x16x32_bf16(qh[mt], bl, s, 0, 0, 0);
                s = __builtin_amdgcn_mfma_f32_16x16x32_bf16(ql[mt], bh, s, 0, 0, 0);
                sf[mt][nt] = s;
            }
        }

        #pragma unroll
        for (int mt = 0; mt < 2; ++mt)
            #pragma unroll
            for (int nt = 0; nt < 4; ++nt)
                #pragma unroll
                for (int r = 0; r < 4; ++r) {
                    const float p = __expf(sf[mt][nt][r]);
                    lacc[mt][r] += p;
                    Ps[qloc + mt * 16 + lq * 4 + r][nt * 16 + lm] = bf16_rne(p);
                }

        #pragma unroll
        for (int kt = 0; kt < 2; ++kt) {
            bf16x8 pa[2];
            #pragma unroll
            for (int mt = 0; mt < 2; ++mt)
                pa[mt] = *(const bf16x8*)&Ps[qloc + mt * 16 + lm][kt * 32 + lq * 8];
            #pragma unroll
            for (int vt = 0; vt < 2; ++vt) {
                const size_t vb = kvhead + ((size_t)(vt * 64 + (j0 >> 3) + kt * 4 + lq) * 16 + lm) * 8;
                bf16x8 bvh = *(const bf16x8*)(vrh + vb);
                bf16x8 bvl = *(const bf16x8*)(vrl + vb);
                #pragma unroll
                for (int mt = 0; mt < 2; ++mt) {
                    o[mt][vt] = __builtin_amdgcn_mfma_f32_16x16x32_bf16(pa[mt], bvh, o[mt][vt], 0, 0, 0);
                    o[mt][vt] = __builtin_amdgcn_mfma_f32_16x16x32_bf16(pa[mt], bvl, o[mt][vt], 0, 0, 0);
                }
            }
        }
    }

    #pragma unroll
    for (int mt = 0; mt < 2; ++mt)
        #pragma unroll
        for (int r = 0; r < 4; ++r) {
            float t = lacc[mt][r];
            t += __shfl_xor(t, 1, 64);
            t += __shfl_xor(t, 2, 64);
            t += __shfl_xor(t, 4, 64);
            t += __shfl_xor(t, 8, 64);
            lacc[mt][r] = 1.f / t;
        }

    // ---- epilogue: normalize + pack into dead Ps (u32 = hi<<16|lo), then
    //      drain as coalesced uint4 stores in A-FRAGMENT order ----
    __syncthreads();                               // all waves done with Ps
    unsigned int* bufU = (unsigned int*)&Ps[0][0]; // 4096 u32 = 16 KB
    const int mtbase0 = (b * 512 + chunk * 128) >> 4;
    const int kcl0 = lm >> 3;                      // 0/1 (x1 goes to +2)
    #pragma unroll
    for (int mt = 0; mt < 2; ++mt) {
        const int lmt = w * 2 + mt;                // local mtile 0..7
        #pragma unroll
        for (int r = 0; r < 4; ++r) {
            const int i = (lq * 4 + r) * 8 + (lm & 7);
            const float x0 = o[mt][0][r] * lacc[mt][r];
            const float x1 = o[mt][1][r] * lacc[mt][r];
            const ushort_t h0 = bf16_rne(x0);
            const ushort_t h1 = bf16_rne(x1);
            const ushort_t l0 = bf16_rne(x0 - __uint_as_float(((unsigned)h0) << 16));
            const ushort_t l1 = bf16_rne(x1 - __uint_as_float(((unsigned)h1) << 16));
            bufU[(lmt * 4 + kcl0) * 128 + i]       = (((unsigned)h0) << 16) | (unsigned)l0;
            bufU[(lmt * 4 + kcl0 + 2) * 128 + i]   = (((unsigned)h1) << 16) | (unsigned)l1;
        }
    }
    __syncthreads();
    // drain: 4096 u32 -> 512 chunks of 8 elems; 256 threads x 2 chunks
    #pragma unroll
    for (int it = 0; it < 2; ++it) {
        const int cid = it * 256 + tid;            // [0, 512)
        const int L   = cid * 8;                   // u32 index
        const int lmt = L >> 9;                    // /512
        const int kcl = (L >> 7) & 3;
        const int i0  = L & 127;
        const unsigned int* p = bufU + L;
        const uint4 a = *(const uint4*)p;
        const uint4 c = *(const uint4*)(p + 4);
        uint4 hi4, lo4;
        hi4.x = (a.x >> 16) | (a.y & 0xffff0000u);
        hi4.y = (a.z >> 16) | (a.w & 0xffff0000u);
        hi4.z = (c.x >> 16) | (c.y & 0xffff0000u);
        hi4.w = (c.z >> 16) | (c.w & 0xffff0000u);
        lo4.x = (a.x & 0xffffu) | (a.y << 16);
        lo4.y = (a.z & 0xffffu) | (a.w << 16);
        lo4.z = (c.x & 0xffffu) | (c.y << 16);
        lo4.w = (c.z & 0xffffu) | (c.w << 16);
        const size_t gaddr = ((size_t)(mtbase0 + lmt) * 384 + (gh * 4 + kcl)) * 128 + i0;
        *(uint4*)(aoh + gaddr) = hi4;
        *(uint4*)(aol + gaddr) = lo4;
    }
}

// ---------------------------------------------------------------------------
// Kernel 4: output projection, split-bf16 MFMA, split-K=8, NO LDS/barriers.
// (split-K=4 tested round-12: regressed — parallelism beats traffic here.)
// ---------------------------------------------------------------------------
__global__ __launch_bounds__(256, 1) void oproj_mfma_kernel(
    const ushort_t* __restrict__ Arh, const ushort_t* __restrict__ Arl,
    const ushort_t* __restrict__ Worh, const ushort_t* __restrict__ Worl,
    float* __restrict__ part)                                 // [8][1024][768]
{
    const int h  = blockIdx.x;
    const int m0 = blockIdx.y * 128;
    const int kz = blockIdx.z;
    const int tid  = threadIdx.x;
    const int lane = tid & 63;
    const int w    = tid >> 6;
    const int wm   = (w >> 1) * 64;
    const int wn   = (w & 1) * 32;
    const int lm   = lane & 15;
    const int lq   = lane >> 4;
    const int tA0  = (m0 + wm) >> 4;
    const int ctb  = wn >> 4;               // 0 or 2

    f32x4 acc[4][2];
    #pragma unroll
    for (int i = 0; i < 4; ++i) { acc[i][0] = (f32x4)(0.0f); acc[i][1] = (f32x4)(0.0f); }

    for (int ks = 0; ks < 12; ++ks) {
        const int k0 = kz * 384 + ks * 32;
        const int g  = k0 >> 8;
        int gp = g - h; if (gp < 0) gp += NG;
        const int kcA = kz * 48 + ks * 4 + lq;
        const int kcB = ((k0 & 255) >> 3) + lq;
        bf16x8 ah[4], al[4], bh[2], bl[2];
        #pragma unroll
        for (int mt = 0; mt < 4; ++mt) {
            const size_t aoff = ((size_t)(tA0 + mt) * 384 + kcA) * 128 + lm * 8;
            ah[mt] = *(const bf16x8*)(Arh + aoff);
            al[mt] = *(const bf16x8*)(Arl + aoff);
        }
        const size_t bbase = ((size_t)(gp * 4 + ctb) * 32 + kcB) * 128 + lm * 8;
        #pragma unroll
        for (int nt = 0; nt < 2; ++nt) {
            bh[nt] = *(const bf16x8*)(Worh + bbase + nt * 4096);
            bl[nt] = *(const bf16x8*)(Worl + bbase + nt * 4096);
        }
        #pragma unroll
        for (int mt = 0; mt < 4; ++mt)
            #pragma unroll
            for (int nt = 0; nt < 2; ++nt) {
                acc[mt][nt] = __builtin_amdgcn_mfma_f32_16x16x32_bf16(ah[mt], bh[nt], acc[mt][nt], 0, 0, 0);
                acc[mt][nt] = __builtin_amdgcn_mfma_f32_16x16x32_bf16(ah[mt], bl[nt], acc[mt][nt], 0, 0, 0);
                acc[mt][nt] = __builtin_amdgcn_mfma_f32_16x16x32_bf16(al[mt], bh[nt], acc[mt][nt], 0, 0, 0);
            }
    }
    float* dst0 = part + (size_t)kz * (NROWS * DOUT);
    #pragma unroll
    for (int mt = 0; mt < 4; ++mt)
        #pragma unroll
        for (int r = 0; r < 4; ++r) {
            float* dst = dst0 + (size_t)(m0 + wm + mt * 16 + lq * 4 + r) * DOUT + h * 64 + wn + lm;
            dst[0]  = acc[mt][0][r];
            dst[16] = acc[mt][1][r];
        }
}

__global__ __launch_bounds__(256) void reduce8_kernel(
    const float* __restrict__ part, float* __restrict__ out)
{
    const int i = blockIdx.x * 256 + threadIdx.x;   // over 196608 float4s
    const float4* p = (const float4*)part;
    const int s = NROWS * DOUT / 4;                 // 196608
    float4 r = p[i];
    #pragma unroll
    for (int j = 1; j < 8; ++j) {
        float4 t = p[i + j * s];
        r.x += t.x; r.y += t.y; r.z += t.z; r.w += t.w;
    }
    ((float4*)out)[i] = r;
}

// ---------------------------------------------------------------------------
extern "C" void kernel_launch(void* const* d_in, const int* in_sizes, int n_in,
                              void* d_out, int out_size, void* d_ws, size_t ws_size,
                              hipStream_t stream)
{
    const float* feat   = (const float*)d_in[0];
    const float* coords = (const float*)d_in[1];
    const float* Wq     = (const float*)d_in[2];
    const float* Wk     = (const float*)d_in[3];
    const float* Wv     = (const float*)d_in[4];
    const float* Wo     = (const float*)d_in[5];
    const float* qw     = (const float*)d_in[6];
    const float* kw     = (const float*)d_in[7];
    const float* pf     = (const float*)d_in[8];
    const int*   seq    = (const int*)d_in[9];

    // regions (SZU floats each): qreg | kreg | vreg | aoreg
    float* qreg  = (float*)d_ws;
    float* kreg  = qreg + SZU;
    float* vreg  = kreg + SZU;
    float* aoreg = vreg + SZU;

    // phase 1: Xr + Wqkv planes in aoreg; WOr planes staged in d_out
    ushort_t* Xrh = (ushort_t*)aoreg;
    ushort_t* Xrl = Xrh + (size_t)NROWS * DIN;               // 786432 each
    ushort_t* Wqh = Xrl + (size_t)NROWS * DIN;
    ushort_t* Wql = Wqh + (size_t)3 * 196608;
    ushort_t* WOrh = (ushort_t*)d_out;
    ushort_t* WOrl = WOrh + (size_t)196608;
    // phase 2: qkv -> q,k,v fp32 in qreg,kreg,vreg.
    // norm_rope (k-only): k fp32 -> Kr planes -> aoreg (Xr/W dead).
    ushort_t* Krh = (ushort_t*)aoreg;
    ushort_t* Krl = Krh + SZU;
    // vpack: Vr planes -> kreg (k fp32 dead after norm_rope).
    ushort_t* Vrh = (ushort_t*)kreg;
    ushort_t* Vrl = Vrh + SZU;
    // attn: AOr planes -> vreg (v fp32 dead after vpack).
    ushort_t* AOrh = (ushort_t*)vreg;
    ushort_t* AOrl = AOrh + SZU;
    // after attn: partials [8][1024][768] = 24 MB -> qreg+kreg (contiguous).
    float*    part = (float*)d_ws;

    prep_kernel<<<dim3(768), 256, 0, stream>>>(feat, Wq, Wk, Wv, Wo,
        Xrh, Xrl, Wqh, Wql, WOrh, WOrl);
    qkv_mfma_kernel<<<dim3(24, 8, 3), 256, 0, stream>>>(Xrh, Xrl, Wqh, Wql, qreg, kreg, vreg);
    norm_rope_kernel<<<dim3(384), 256, 0, stream>>>(kreg, Krh, Krl, coords, seq, kw, pf);
    vpack_kernel<<<dim3(1536), 256, 0, stream>>>(vreg, Vrh, Vrl);
    attn_mfma_kernel<<<dim3(96, 4, 2), 256, 0, stream>>>(qreg, Krh, Krl, Vrh, Vrl, AOrh, AOrl,
                                                         coords, seq, qw, pf);
    oproj_mfma_kernel<<<dim3(12, 8, 8), 256, 0, stream>>>(AOrh, AOrl, WOrh, WOrl, part);
    reduce8_kernel<<<dim3(768), 256, 0, stream>>>(part, (float*)d_out);
}

// Round 14
// 198.675 us; speedup vs baseline: 1.0603x; 1.0195x over previous
//
#include <hip/hip_runtime.h>
#include <math.h>

// Problem constants
#define NG   12
#define NH   8
#define CIN  64
#define CQK  32
#define CVAL 32
#define COUT 64
#define NB   2
#define NN   512
#define NROWS (NB * NN)     // 1024
#define GHH  (NG * NH)      // 96 heads
#define DIN  (NG * CIN)     // 768
#define DQK  (GHH * CQK)    // 3072
#define DOUT (NG * COUT)    // 768

typedef __attribute__((ext_vector_type(8))) short bf16x8;
typedef __attribute__((ext_vector_type(4))) float f32x4;
typedef unsigned short ushort_t;

#define SZU ((size_t)NROWS * DQK)   // 3145728 elements per fp32 region

__device__ __forceinline__ ushort_t bf16_rne(float v) {
    unsigned u = __float_as_uint(v);
    return (ushort_t)((u + 0x7fffu + ((u >> 16) & 1u)) >> 16);
}

// ---------------------------------------------------------------------------
// Fused prep (block-range dispatch):
// blocks [0,384):   X split + swizzle into A-frag order
// blocks [384,672): Wq/Wk/Wv split + swizzle into B-frag order
// blocks [672,768): Wo split + swizzle -> WOr planes staged in d_out
// ---------------------------------------------------------------------------
__global__ __launch_bounds__(256) void prep_kernel(
    const float* __restrict__ feat,
    const float* __restrict__ Wq, const float* __restrict__ Wk,
    const float* __restrict__ Wv, const float* __restrict__ Wo,
    ushort_t* __restrict__ Xrh, ushort_t* __restrict__ Xrl,
    ushort_t* __restrict__ Wqh, ushort_t* __restrict__ Wql,
    ushort_t* __restrict__ WOrh, ushort_t* __restrict__ WOrl)
{
    const int bb = blockIdx.x;
    if (bb < 384) {
        const int t  = bb * 256 + threadIdx.x;   // [0, 98304)
        const int mr  = t & 15;
        const int u   = t >> 4;
        const int kc  = u % 96;
        const int m16 = u / 96;
        const float* src = feat + (size_t)(m16 * 16 + mr) * DIN + kc * 8;
        float v[8];
        *(float4*)v       = *(const float4*)src;
        *(float4*)(v + 4) = *(const float4*)(src + 4);
        ushort_t h8[8] __attribute__((aligned(16)));
        ushort_t l8[8] __attribute__((aligned(16)));
        #pragma unroll
        for (int j = 0; j < 8; ++j) {
            ushort_t hb = bf16_rne(v[j]);
            float hf = __uint_as_float(((unsigned)hb) << 16);
            h8[j] = hb;
            l8[j] = bf16_rne(v[j] - hf);
        }
        const size_t dst = ((size_t)m16 * 96 + kc) * 128 + mr * 8;
        *(uint4*)(Xrh + dst) = *(const uint4*)h8;
        *(uint4*)(Xrl + dst) = *(const uint4*)l8;
    } else if (bb < 672) {
        const int zz = (bb - 384) / 96;
        const float* W = (zz == 0) ? Wq : (zz == 1) ? Wk : Wv;
        ushort_t* hi = Wqh + (size_t)zz * 196608;
        ushort_t* lo = Wql + (size_t)zz * 196608;
        const int t  = ((bb - 384) % 96) * 256 + threadIdx.x;   // [0, 24576)
        const int kc = t & 7;
        const int o  = (t >> 3) & 255;
        const int gp = t >> 11;
        const float* src = W + ((size_t)(gp * 256 + o)) * 64 + kc * 8;
        float v[8];
        *(float4*)v       = *(const float4*)src;
        *(float4*)(v + 4) = *(const float4*)(src + 4);
        ushort_t h8[8] __attribute__((aligned(16)));
        ushort_t l8[8] __attribute__((aligned(16)));
        #pragma unroll
        for (int j = 0; j < 8; ++j) {
            ushort_t hb = bf16_rne(v[j]);
            float hf = __uint_as_float(((unsigned)hb) << 16);
            h8[j] = hb;
            l8[j] = bf16_rne(v[j] - hf);
        }
        const size_t dst = ((size_t)(gp * 16 + (o >> 4)) * 8 + kc) * 128 + (o & 15) * 8;
        *(uint4*)(hi + dst) = *(const uint4*)h8;
        *(uint4*)(lo + dst) = *(const uint4*)l8;
    } else {
        const int t  = (bb - 672) * 256 + threadIdx.x;   // [0, 24576)
        const int kc = t & 31;
        const int o  = (t >> 5) & 63;
        const int gp = t >> 11;
        const float* src = Wo + ((size_t)(gp * 64 + o)) * 256 + kc * 8;
        float v[8];
        *(float4*)v       = *(const float4*)src;
        *(float4*)(v + 4) = *(const float4*)(src + 4);
        ushort_t h8[8] __attribute__((aligned(16)));
        ushort_t l8[8] __attribute__((aligned(16)));
        #pragma unroll
        for (int j = 0; j < 8; ++j) {
            ushort_t hb = bf16_rne(v[j]);
            float hf = __uint_as_float(((unsigned)hb) << 16);
            h8[j] = hb;
            l8[j] = bf16_rne(v[j] - hf);
        }
        const size_t dst = ((size_t)(gp * 4 + (o >> 4)) * 32 + kc) * 128 + (o & 15) * 8;
        *(uint4*)(WOrh + dst) = *(const uint4*)h8;
        *(uint4*)(WOrl + dst) = *(const uint4*)l8;
    }
}

// ---------------------------------------------------------------------------
// Kernel 1: block-circulant QKV projection — EXACT round-0 body, DO NOT TOUCH
// (10 failed variants: ILP/TLP/locality/fusion/tiling all regress).
// ---------------------------------------------------------------------------
__global__ __launch_bounds__(256, 1) void qkv_mfma_kernel(
    const ushort_t* __restrict__ Xrh, const ushort_t* __restrict__ Xrl,
    const ushort_t* __restrict__ Wrh, const ushort_t* __restrict__ Wrl,
    float* __restrict__ qo, float* __restrict__ ko, float* __restrict__ vo)
{
    const int z = blockIdx.z;
    float* __restrict__ out = (z == 0) ? qo : (z == 1) ? ko : vo;
    const ushort_t* Wh = Wrh + (size_t)z * 196608;
    const ushort_t* Wl = Wrl + (size_t)z * 196608;
    const int m0 = blockIdx.y * 128;
    const int c0 = blockIdx.x * 128;
    const int hg = c0 >> 8;
    const int o0 = c0 & 255;
    const int tid  = threadIdx.x;
    const int lane = tid & 63;
    const int w    = tid >> 6;
    const int wm   = (w >> 1) * 64;
    const int wn   = (w & 1) * 64;
    const int lm   = lane & 15;
    const int lq   = lane >> 4;
    const int tA0  = (m0 + wm) >> 4;
    const int ct0  = (o0 + wn) >> 4;

    f32x4 acc[4][4];
    #pragma unroll
    for (int i = 0; i < 4; ++i)
        #pragma unroll
        for (int j = 0; j < 4; ++j) acc[i][j] = (f32x4)(0.0f);

    for (int ks = 0; ks < 24; ++ks) {
        const int g = ks >> 1;
        int gp = g - hg; if (gp < 0) gp += NG;
        bf16x8 ah[4], al[4], bh[4], bl[4];
        #pragma unroll
        for (int mt = 0; mt < 4; ++mt) {
            const size_t aoff = ((size_t)(tA0 + mt) * 96 + ks * 4 + lq) * 128 + lm * 8;
            ah[mt] = *(const bf16x8*)(Xrh + aoff);
            al[mt] = *(const bf16x8*)(Xrl + aoff);
        }
        const size_t bbase = ((size_t)(gp * 16 + ct0) * 8 + (ks & 1) * 4 + lq) * 128 + lm * 8;
        #pragma unroll
        for (int nt = 0; nt < 4; ++nt) {
            bh[nt] = *(const bf16x8*)(Wh + bbase + nt * 1024);
            bl[nt] = *(const bf16x8*)(Wl + bbase + nt * 1024);
        }
        #pragma unroll
        for (int mt = 0; mt < 4; ++mt)
            #pragma unroll
            for (int nt = 0; nt < 4; ++nt) {
                acc[mt][nt] = __builtin_amdgcn_mfma_f32_16x16x32_bf16(ah[mt], bh[nt], acc[mt][nt], 0, 0, 0);
                acc[mt][nt] = __builtin_amdgcn_mfma_f32_16x16x32_bf16(ah[mt], bl[nt], acc[mt][nt], 0, 0, 0);
                acc[mt][nt] = __builtin_amdgcn_mfma_f32_16x16x32_bf16(al[mt], bh[nt], acc[mt][nt], 0, 0, 0);
            }
    }
    #pragma unroll
    for (int mt = 0; mt < 4; ++mt)
        #pragma unroll
        for (int r = 0; r < 4; ++r) {
            float* dst = out + (size_t)(m0 + wm + mt * 16 + lq * 4 + r) * DQK + c0 + wn + lm;
            #pragma unroll
            for (int nt = 0; nt < 4; ++nt) dst[nt * 16] = acc[mt][nt][r];
        }
}

// ---------------------------------------------------------------------------
// Kernel 2: K-ONLY RMSNorm + fused ropes -> split-bf16 Kr B-fragment planes.
// ---------------------------------------------------------------------------
__global__ __launch_bounds__(256) void norm_rope_kernel(
    const float* __restrict__ kin,
    ushort_t* __restrict__ krh, ushort_t* __restrict__ krl,
    const float* __restrict__ coords,
    const int* __restrict__ seq,
    const float* __restrict__ kw,
    const float* __restrict__ pf)
{
    const int hid = blockIdx.x * 256 + threadIdx.x;
    const int gh = hid % GHH;
    const int bn = hid / GHH;
    const int g = gh >> 3;
    const int h = gh & 7;
    const float* kp = kin + (size_t)hid * CQK;
    float xk[CQK];
    #pragma unroll
    for (int u = 0; u < 8; ++u) *(float4*)(xk + 4 * u) = *(const float4*)(kp + 4 * u);

    float sk = 0.f;
    #pragma unroll
    for (int c = 0; c < CQK; ++c) sk = fmaf(xk[c], xk[c], sk);
    const float eps = 1.1920928955078125e-07f;
    const float invk = rsqrtf(sk * (1.f / CQK) + eps);
    #pragma unroll
    for (int c = 0; c < CQK; ++c) xk[c] *= invk * kw[c];

    const float pos = (float)seq[bn];
    const float cx = coords[bn * 3 + 0], cy = coords[bn * 3 + 1], cz = coords[bn * 3 + 2];
    float sg, cg;
    sincosf((float)g * 0.5235987755982988f, &sg, &cg);
    const float u0 = cg * cx + sg * cy;
    const float u1 = cg * cy - sg * cx;
    const float u2 = cz;

    #pragma unroll
    for (int f = 0; f < 16; ++f) {
        const float invf = exp2f(-(float)f * 0.8304820237218405f);
        const float* fr = pf + ((size_t)h * 16 + f) * 3;
        const float ang = fmaf(pos, invf, u0 * fr[0] + u1 * fr[1] + u2 * fr[2]);
        float sn, cs;
        sincosf(ang, &sn, &cs);
        float b1 = xk[2 * f], b2 = xk[2 * f + 1];
        xk[2 * f]     = b1 * cs - b2 * sn;
        xk[2 * f + 1] = b1 * sn + b2 * cs;
    }

    const int b = bn >> 9, n = bn & 511;
    const size_t kbase = (((size_t)(b * GHH + gh) * 32 + (n >> 4)) * 4) * 128 + (n & 15) * 8;
    #pragma unroll
    for (int kc = 0; kc < 4; ++kc) {
        ushort_t h8[8] __attribute__((aligned(16)));
        ushort_t l8[8] __attribute__((aligned(16)));
        #pragma unroll
        for (int j = 0; j < 8; ++j) {
            const float x = xk[kc * 8 + j];
            const ushort_t hb = bf16_rne(x);
            h8[j] = hb;
            l8[j] = bf16_rne(x - __uint_as_float(((unsigned)hb) << 16));
        }
        *(uint4*)(krh + kbase + kc * 128) = *(const uint4*)h8;
        *(uint4*)(krl + kbase + kc * 128) = *(const uint4*)l8;
    }
}

// ---------------------------------------------------------------------------
// Kernel 2b: V pack — fp32 V -> split-bf16 V^T B-fragment planes.
// ---------------------------------------------------------------------------
__global__ __launch_bounds__(256) void vpack_kernel(
    const float* __restrict__ v,
    ushort_t* __restrict__ vrh, ushort_t* __restrict__ vrl)
{
    const int t  = blockIdx.x * 256 + threadIdx.x;   // [0, 393216)
    const int vd = t & 31;
    const int kc = (t >> 5) & 63;
    const int bg = t >> 11;                          // [0, 192)
    const int b  = (bg >= GHH) ? 1 : 0;
    const int gh = bg - b * GHH;
    const float* src = v + (size_t)(b * 512 + kc * 8) * DQK + gh * 32 + vd;
    ushort_t h8[8] __attribute__((aligned(16)));
    ushort_t l8[8] __attribute__((aligned(16)));
    #pragma unroll
    for (int j = 0; j < 8; ++j) {
        const float x = src[j * DQK];
        const ushort_t hb = bf16_rne(x);
        h8[j] = hb;
        l8[j] = bf16_rne(x - __uint_as_float(((unsigned)hb) << 16));
    }
    const size_t dst = ((size_t)(bg * 2 + (vd >> 4)) * 64 + kc) * 128 + (vd & 15) * 8;
    *(uint4*)(vrh + dst) = *(const uint4*)h8;
    *(uint4*)(vrl + dst) = *(const uint4*)l8;
}

// ---------------------------------------------------------------------------
// Kernel 3: MFMA flash attention, NO-MAX softmax; q norm+rope in prologue;
// AO epilogue via dead-Ps LDS repack.
// Round-14: QBLK 128 -> 64 (mt dim removed, grid y 4 -> 8 = 1536 blocks,
// 6/CU) — double TLP at identical per-wave instruction pattern; K/V L2
// re-reads double (cheap, L2-resident). Parallelism-beats-traffic principle.
// ---------------------------------------------------------------------------
__global__ __launch_bounds__(256, 1) void attn_mfma_kernel(
    const float* __restrict__ q,
    const ushort_t* __restrict__ krh, const ushort_t* __restrict__ krl,
    const ushort_t* __restrict__ vrh, const ushort_t* __restrict__ vrl,
    ushort_t* __restrict__ aoh,     // A-frag order [m>>4][384][16][8]
    ushort_t* __restrict__ aol,
    const float* __restrict__ coords, const int* __restrict__ seq,
    const float* __restrict__ qw, const float* __restrict__ pf)
{
    __shared__ __attribute__((aligned(16))) ushort_t Ps[64][72];

    const int gh    = blockIdx.x;
    const int chunk = blockIdx.y;          // 8 chunks of 64 q-rows
    const int b     = blockIdx.z;
    const size_t headoff = (size_t)b * NN * DQK + (size_t)gh * CQK;
    const size_t kvhead = (size_t)(b * GHH + gh) * 16384;
    const int tid  = threadIdx.x;
    const int lane = tid & 63;
    const int w    = tid >> 6;
    const int lm   = lane & 15;
    const int lq   = lane >> 4;       // quad
    const int qloc = w * 16;          // wave's local q-row base (0..48)

    const int hh = gh & 7;
    float sg, cg;
    sincosf((float)(gh >> 3) * 0.5235987755982988f, &sg, &cg);
    float invf[4], fr0[4], fr1[4], fr2[4];
    #pragma unroll
    for (int u = 0; u < 4; ++u) {
        const int f = lq * 4 + u;
        invf[u] = exp2f(-(float)f * 0.8304820237218405f);
        const float* fr = pf + ((size_t)hh * 16 + f) * 3;
        fr0[u] = fr[0]; fr1[u] = fr[1]; fr2[u] = fr[2];
    }
    float qwv[8];
    *(float4*)qwv       = *(const float4*)(qw + lq * 8);
    *(float4*)(qwv + 4) = *(const float4*)(qw + lq * 8 + 4);

    const float scale = 0.17677669529663687f;  // 1/sqrt(32)
    const float eps = 1.1920928955078125e-07f;
    bf16x8 qh, ql;
    {
        const int row = chunk * 64 + qloc + lm;
        const int bn  = b * NN + row;
        const float* qp = q + headoff + (size_t)row * DQK + lq * 8;
        float4 t0 = *(const float4*)qp;
        float4 t1 = *(const float4*)(qp + 4);
        float vals[8] = {t0.x, t0.y, t0.z, t0.w, t1.x, t1.y, t1.z, t1.w};

        float ss = 0.f;
        #pragma unroll
        for (int j = 0; j < 8; ++j) ss = fmaf(vals[j], vals[j], ss);
        ss += __shfl_xor(ss, 16, 64);
        ss += __shfl_xor(ss, 32, 64);
        const float inv = rsqrtf(ss * (1.0f / 32.0f) + eps);

        const float pos = (float)seq[bn];
        const float cx = coords[bn * 3], cy = coords[bn * 3 + 1], cz = coords[bn * 3 + 2];
        const float u0 = cg * cx + sg * cy;
        const float u1 = cg * cy - sg * cx;
        const float u2 = cz;

        float o8[8];
        #pragma unroll
        for (int u = 0; u < 4; ++u) {
            const float ang = fmaf(pos, invf[u], u0 * fr0[u] + u1 * fr1[u] + u2 * fr2[u]);
            float sn, cs;
            sincosf(ang, &sn, &cs);
            const float x1 = vals[2 * u]     * inv * qwv[2 * u];
            const float x2 = vals[2 * u + 1] * inv * qwv[2 * u + 1];
            o8[2 * u]     = x1 * cs - x2 * sn;
            o8[2 * u + 1] = x1 * sn + x2 * cs;
        }

        short h8[8], l8[8];
        #pragma unroll
        for (int j = 0; j < 8; ++j) {
            float x = o8[j] * scale;
            ushort_t hb = bf16_rne(x);
            float hf = __uint_as_float(((unsigned)hb) << 16);
            h8[j] = (short)hb;
            l8[j] = (short)bf16_rne(x - hf);
        }
        qh = *(bf16x8*)h8;
        ql = *(bf16x8*)l8;
    }

    float lacc[4];
    f32x4 o[2];
    #pragma unroll
    for (int r = 0; r < 4; ++r) lacc[r] = 0.f;
    o[0] = (f32x4)(0.0f); o[1] = (f32x4)(0.0f);

    for (int j0 = 0; j0 < NN; j0 += 64) {
        // ---- S = Q K^T for 64 keys (4 n-tiles), K frags from global ----
        f32x4 sf[4];
        #pragma unroll
        for (int nt = 0; nt < 4; ++nt) {
            const size_t kb = kvhead + ((size_t)(((j0 >> 4) + nt) * 4 + lq)) * 128 + lm * 8;
            bf16x8 bh = *(const bf16x8*)(krh + kb);
            bf16x8 bl = *(const bf16x8*)(krl + kb);
            f32x4 s = (f32x4)(0.0f);
            s = __builtin_amdgcn_mfma_f32_16x16x32_bf16(qh, bh, s, 0, 0, 0);
            s = __builtin_amdgcn_mfma_f32_16x16x32_bf16(qh, bl, s, 0, 0, 0);
            s = __builtin_amdgcn_mfma_f32_16x16x32_bf16(ql, bh, s, 0, 0, 0);
            sf[nt] = s;
        }

        // ---- p = exp(s); per-lane row-sum; P (bf16) -> wave-private LDS ----
        #pragma unroll
        for (int nt = 0; nt < 4; ++nt)
            #pragma unroll
            for (int r = 0; r < 4; ++r) {
                const float p = __expf(sf[nt][r]);
                lacc[r] += p;
                Ps[qloc + lq * 4 + r][nt * 16 + lm] = bf16_rne(p);
            }

        // ---- O += P V (no barrier: Ps rows wave-private) ----
        #pragma unroll
        for (int kt = 0; kt < 2; ++kt) {
            bf16x8 pa = *(const bf16x8*)&Ps[qloc + lm][kt * 32 + lq * 8];
            #pragma unroll
            for (int vt = 0; vt < 2; ++vt) {
                const size_t vb = kvhead + ((size_t)(vt * 64 + (j0 >> 3) + kt * 4 + lq) * 16 + lm) * 8;
                bf16x8 bvh = *(const bf16x8*)(vrh + vb);
                bf16x8 bvl = *(const bf16x8*)(vrl + vb);
                o[vt] = __builtin_amdgcn_mfma_f32_16x16x32_bf16(pa, bvh, o[vt], 0, 0, 0);
                o[vt] = __builtin_amdgcn_mfma_f32_16x16x32_bf16(pa, bvl, o[vt], 0, 0, 0);
            }
        }
    }

    // ---- single end-of-kernel l reduction over the 16 col-lanes ----
    #pragma unroll
    for (int r = 0; r < 4; ++r) {
        float t = lacc[r];
        t += __shfl_xor(t, 1, 64);
        t += __shfl_xor(t, 2, 64);
        t += __shfl_xor(t, 4, 64);
        t += __shfl_xor(t, 8, 64);
        lacc[r] = 1.f / t;
    }

    // ---- epilogue: normalize + pack into dead Ps (u32 = hi<<16|lo), then
    //      drain as coalesced uint4 stores in A-FRAGMENT order ----
    __syncthreads();                               // all waves done with Ps
    unsigned int* bufU = (unsigned int*)&Ps[0][0]; // 2048 u32 = 8 KB
    const int mtbase0 = (b * 512 + chunk * 64) >> 4;
    const int kcl0 = lm >> 3;                      // 0/1 (x1 goes to +2)
    {
        const int lmt = w;                         // local mtile 0..3
        #pragma unroll
        for (int r = 0; r < 4; ++r) {
            const int i = (lq * 4 + r) * 8 + (lm & 7);
            const float x0 = o[0][r] * lacc[r];
            const float x1 = o[1][r] * lacc[r];
            const ushort_t h0 = bf16_rne(x0);
            const ushort_t h1 = bf16_rne(x1);
            const ushort_t l0 = bf16_rne(x0 - __uint_as_float(((unsigned)h0) << 16));
            const ushort_t l1 = bf16_rne(x1 - __uint_as_float(((unsigned)h1) << 16));
            bufU[(lmt * 4 + kcl0) * 128 + i]       = (((unsigned)h0) << 16) | (unsigned)l0;
            bufU[(lmt * 4 + kcl0 + 2) * 128 + i]   = (((unsigned)h1) << 16) | (unsigned)l1;
        }
    }
    __syncthreads();
    // drain: 2048 u32 -> 256 chunks of 8 elems; 256 threads x 1 chunk
    {
        const int L   = tid * 8;                   // u32 index
        const int lmt = L >> 9;                    // /512
        const int kcl = (L >> 7) & 3;
        const int i0  = L & 127;
        const unsigned int* p = bufU + L;
        const uint4 a = *(const uint4*)p;
        const uint4 c = *(const uint4*)(p + 4);
        uint4 hi4, lo4;
        hi4.x = (a.x >> 16) | (a.y & 0xffff0000u);
        hi4.y = (a.z >> 16) | (a.w & 0xffff0000u);
        hi4.z = (c.x >> 16) | (c.y & 0xffff0000u);
        hi4.w = (c.z >> 16) | (c.w & 0xffff0000u);
        lo4.x = (a.x & 0xffffu) | (a.y << 16);
        lo4.y = (a.z & 0xffffu) | (a.w << 16);
        lo4.z = (c.x & 0xffffu) | (c.y << 16);
        lo4.w = (c.z & 0xffffu) | (c.w << 16);
        const size_t gaddr = ((size_t)(mtbase0 + lmt) * 384 + (gh * 4 + kcl)) * 128 + i0;
        *(uint4*)(aoh + gaddr) = hi4;
        *(uint4*)(aol + gaddr) = lo4;
    }
}

// ---------------------------------------------------------------------------
// Kernel 4: output projection, split-bf16 MFMA, split-K=8, NO LDS/barriers.
// (split-K=4 tested round-12: regressed — parallelism beats traffic here.)
// ---------------------------------------------------------------------------
__global__ __launch_bounds__(256, 1) void oproj_mfma_kernel(
    const ushort_t* __restrict__ Arh, const ushort_t* __restrict__ Arl,
    const ushort_t* __restrict__ Worh, const ushort_t* __restrict__ Worl,
    float* __restrict__ part)                                 // [8][1024][768]
{
    const int h  = blockIdx.x;
    const int m0 = blockIdx.y * 128;
    const int kz = blockIdx.z;
    const int tid  = threadIdx.x;
    const int lane = tid & 63;
    const int w    = tid >> 6;
    const int wm   = (w >> 1) * 64;
    const int wn   = (w & 1) * 32;
    const int lm   = lane & 15;
    const int lq   = lane >> 4;
    const int tA0  = (m0 + wm) >> 4;
    const int ctb  = wn >> 4;               // 0 or 2

    f32x4 acc[4][2];
    #pragma unroll
    for (int i = 0; i < 4; ++i) { acc[i][0] = (f32x4)(0.0f); acc[i][1] = (f32x4)(0.0f); }

    for (int ks = 0; ks < 12; ++ks) {
        const int k0 = kz * 384 + ks * 32;
        const int g  = k0 >> 8;
        int gp = g - h; if (gp < 0) gp += NG;
        const int kcA = kz * 48 + ks * 4 + lq;
        const int kcB = ((k0 & 255) >> 3) + lq;
        bf16x8 ah[4], al[4], bh[2], bl[2];
        #pragma unroll
        for (int mt = 0; mt < 4; ++mt) {
            const size_t aoff = ((size_t)(tA0 + mt) * 384 + kcA) * 128 + lm * 8;
            ah[mt] = *(const bf16x8*)(Arh + aoff);
            al[mt] = *(const bf16x8*)(Arl + aoff);
        }
        const size_t bbase = ((size_t)(gp * 4 + ctb) * 32 + kcB) * 128 + lm * 8;
        #pragma unroll
        for (int nt = 0; nt < 2; ++nt) {
            bh[nt] = *(const bf16x8*)(Worh + bbase + nt * 4096);
            bl[nt] = *(const bf16x8*)(Worl + bbase + nt * 4096);
        }
        #pragma unroll
        for (int mt = 0; mt < 4; ++mt)
            #pragma unroll
            for (int nt = 0; nt < 2; ++nt) {
                acc[mt][nt] = __builtin_amdgcn_mfma_f32_16x16x32_bf16(ah[mt], bh[nt], acc[mt][nt], 0, 0, 0);
                acc[mt][nt] = __builtin_amdgcn_mfma_f32_16x16x32_bf16(ah[mt], bl[nt], acc[mt][nt], 0, 0, 0);
                acc[mt][nt] = __builtin_amdgcn_mfma_f32_16x16x32_bf16(al[mt], bh[nt], acc[mt][nt], 0, 0, 0);
            }
    }
    float* dst0 = part + (size_t)kz * (NROWS * DOUT);
    #pragma unroll
    for (int mt = 0; mt < 4; ++mt)
        #pragma unroll
        for (int r = 0; r < 4; ++r) {
            float* dst = dst0 + (size_t)(m0 + wm + mt * 16 + lq * 4 + r) * DOUT + h * 64 + wn + lm;
            dst[0]  = acc[mt][0][r];
            dst[16] = acc[mt][1][r];
        }
}

__global__ __launch_bounds__(256) void reduce8_kernel(
    const float* __restrict__ part, float* __restrict__ out)
{
    const int i = blockIdx.x * 256 + threadIdx.x;   // over 196608 float4s
    const float4* p = (const float4*)part;
    const int s = NROWS * DOUT / 4;                 // 196608
    float4 r = p[i];
    #pragma unroll
    for (int j = 1; j < 8; ++j) {
        float4 t = p[i + j * s];
        r.x += t.x; r.y += t.y; r.z += t.z; r.w += t.w;
    }
    ((float4*)out)[i] = r;
}

// ---------------------------------------------------------------------------
extern "C" void kernel_launch(void* const* d_in, const int* in_sizes, int n_in,
                              void* d_out, int out_size, void* d_ws, size_t ws_size,
                              hipStream_t stream)
{
    const float* feat   = (const float*)d_in[0];
    const float* coords = (const float*)d_in[1];
    const float* Wq     = (const float*)d_in[2];
    const float* Wk     = (const float*)d_in[3];
    const float* Wv     = (const float*)d_in[4];
    const float* Wo     = (const float*)d_in[5];
    const float* qw     = (const float*)d_in[6];
    const float* kw     = (const float*)d_in[7];
    const float* pf     = (const float*)d_in[8];
    const int*   seq    = (const int*)d_in[9];

    // regions (SZU floats each): qreg | kreg | vreg | aoreg
    float* qreg  = (float*)d_ws;
    float* kreg  = qreg + SZU;
    float* vreg  = kreg + SZU;
    float* aoreg = vreg + SZU;

    // phase 1: Xr + Wqkv planes in aoreg; WOr planes staged in d_out
    ushort_t* Xrh = (ushort_t*)aoreg;
    ushort_t* Xrl = Xrh + (size_t)NROWS * DIN;               // 786432 each
    ushort_t* Wqh = Xrl + (size_t)NROWS * DIN;
    ushort_t* Wql = Wqh + (size_t)3 * 196608;
    ushort_t* WOrh = (ushort_t*)d_out;
    ushort_t* WOrl = WOrh + (size_t)196608;
    // phase 2: qkv -> q,k,v fp32 in qreg,kreg,vreg.
    // norm_rope (k-only): k fp32 -> Kr planes -> aoreg (Xr/W dead).
    ushort_t* Krh = (ushort_t*)aoreg;
    ushort_t* Krl = Krh + SZU;
    // vpack: Vr planes -> kreg (k fp32 dead after norm_rope).
    ushort_t* Vrh = (ushort_t*)kreg;
    ushort_t* Vrl = Vrh + SZU;
    // attn: AOr planes -> vreg (v fp32 dead after vpack).
    ushort_t* AOrh = (ushort_t*)vreg;
    ushort_t* AOrl = AOrh + SZU;
    // after attn: partials [8][1024][768] = 24 MB -> qreg+kreg (contiguous).
    float*    part = (float*)d_ws;

    prep_kernel<<<dim3(768), 256, 0, stream>>>(feat, Wq, Wk, Wv, Wo,
        Xrh, Xrl, Wqh, Wql, WOrh, WOrl);
    qkv_mfma_kernel<<<dim3(24, 8, 3), 256, 0, stream>>>(Xrh, Xrl, Wqh, Wql, qreg, kreg, vreg);
    norm_rope_kernel<<<dim3(384), 256, 0, stream>>>(kreg, Krh, Krl, coords, seq, kw, pf);
    vpack_kernel<<<dim3(1536), 256, 0, stream>>>(vreg, Vrh, Vrl);
    attn_mfma_kernel<<<dim3(96, 8, 2), 256, 0, stream>>>(qreg, Krh, Krl, Vrh, Vrl, AOrh, AOrl,
                                                         coords, seq, qw, pf);
    oproj_mfma_kernel<<<dim3(12, 8, 8), 256, 0, stream>>>(AOrh, AOrl, WOrh, WOrl, part);
    reduce8_kernel<<<dim3(768), 256, 0, stream>>>(part, (float*)d_out);
}

// Round 15
// 197.907 us; speedup vs baseline: 1.0644x; 1.0039x over previous
//
#include <hip/hip_runtime.h>
#include <math.h>

// Problem constants
#define NG   12
#define NH   8
#define CIN  64
#define CQK  32
#define CVAL 32
#define COUT 64
#define NB   2
#define NN   512
#define NROWS (NB * NN)     // 1024
#define GHH  (NG * NH)      // 96 heads
#define DIN  (NG * CIN)     // 768
#define DQK  (GHH * CQK)    // 3072
#define DOUT (NG * COUT)    // 768

typedef __attribute__((ext_vector_type(8))) short bf16x8;
typedef __attribute__((ext_vector_type(4))) float f32x4;
typedef unsigned short ushort_t;

#define SZU ((size_t)NROWS * DQK)   // 3145728 elements per fp32 region

__device__ __forceinline__ ushort_t bf16_rne(float v) {
    unsigned u = __float_as_uint(v);
    return (ushort_t)((u + 0x7fffu + ((u >> 16) & 1u)) >> 16);
}

// ---------------------------------------------------------------------------
// Fused prep (block-range dispatch):
// blocks [0,384):   X split + swizzle into A-frag order
// blocks [384,672): Wq/Wk/Wv split + swizzle into B-frag order
// blocks [672,768): Wo split + swizzle -> WOr planes staged in d_out
// ---------------------------------------------------------------------------
__global__ __launch_bounds__(256) void prep_kernel(
    const float* __restrict__ feat,
    const float* __restrict__ Wq, const float* __restrict__ Wk,
    const float* __restrict__ Wv, const float* __restrict__ Wo,
    ushort_t* __restrict__ Xrh, ushort_t* __restrict__ Xrl,
    ushort_t* __restrict__ Wqh, ushort_t* __restrict__ Wql,
    ushort_t* __restrict__ WOrh, ushort_t* __restrict__ WOrl)
{
    const int bb = blockIdx.x;
    if (bb < 384) {
        const int t  = bb * 256 + threadIdx.x;   // [0, 98304)
        const int mr  = t & 15;
        const int u   = t >> 4;
        const int kc  = u % 96;
        const int m16 = u / 96;
        const float* src = feat + (size_t)(m16 * 16 + mr) * DIN + kc * 8;
        float v[8];
        *(float4*)v       = *(const float4*)src;
        *(float4*)(v + 4) = *(const float4*)(src + 4);
        ushort_t h8[8] __attribute__((aligned(16)));
        ushort_t l8[8] __attribute__((aligned(16)));
        #pragma unroll
        for (int j = 0; j < 8; ++j) {
            ushort_t hb = bf16_rne(v[j]);
            float hf = __uint_as_float(((unsigned)hb) << 16);
            h8[j] = hb;
            l8[j] = bf16_rne(v[j] - hf);
        }
        const size_t dst = ((size_t)m16 * 96 + kc) * 128 + mr * 8;
        *(uint4*)(Xrh + dst) = *(const uint4*)h8;
        *(uint4*)(Xrl + dst) = *(const uint4*)l8;
    } else if (bb < 672) {
        const int zz = (bb - 384) / 96;
        const float* W = (zz == 0) ? Wq : (zz == 1) ? Wk : Wv;
        ushort_t* hi = Wqh + (size_t)zz * 196608;
        ushort_t* lo = Wql + (size_t)zz * 196608;
        const int t  = ((bb - 384) % 96) * 256 + threadIdx.x;   // [0, 24576)
        const int kc = t & 7;
        const int o  = (t >> 3) & 255;
        const int gp = t >> 11;
        const float* src = W + ((size_t)(gp * 256 + o)) * 64 + kc * 8;
        float v[8];
        *(float4*)v       = *(const float4*)src;
        *(float4*)(v + 4) = *(const float4*)(src + 4);
        ushort_t h8[8] __attribute__((aligned(16)));
        ushort_t l8[8] __attribute__((aligned(16)));
        #pragma unroll
        for (int j = 0; j < 8; ++j) {
            ushort_t hb = bf16_rne(v[j]);
            float hf = __uint_as_float(((unsigned)hb) << 16);
            h8[j] = hb;
            l8[j] = bf16_rne(v[j] - hf);
        }
        const size_t dst = ((size_t)(gp * 16 + (o >> 4)) * 8 + kc) * 128 + (o & 15) * 8;
        *(uint4*)(hi + dst) = *(const uint4*)h8;
        *(uint4*)(lo + dst) = *(const uint4*)l8;
    } else {
        const int t  = (bb - 672) * 256 + threadIdx.x;   // [0, 24576)
        const int kc = t & 31;
        const int o  = (t >> 5) & 63;
        const int gp = t >> 11;
        const float* src = Wo + ((size_t)(gp * 64 + o)) * 256 + kc * 8;
        float v[8];
        *(float4*)v       = *(const float4*)src;
        *(float4*)(v + 4) = *(const float4*)(src + 4);
        ushort_t h8[8] __attribute__((aligned(16)));
        ushort_t l8[8] __attribute__((aligned(16)));
        #pragma unroll
        for (int j = 0; j < 8; ++j) {
            ushort_t hb = bf16_rne(v[j]);
            float hf = __uint_as_float(((unsigned)hb) << 16);
            h8[j] = hb;
            l8[j] = bf16_rne(v[j] - hf);
        }
        const size_t dst = ((size_t)(gp * 4 + (o >> 4)) * 32 + kc) * 128 + (o & 15) * 8;
        *(uint4*)(WOrh + dst) = *(const uint4*)h8;
        *(uint4*)(WOrl + dst) = *(const uint4*)l8;
    }
}

// ---------------------------------------------------------------------------
// Kernel 1: block-circulant QKV projection — EXACT round-0 body, DO NOT TOUCH
// (10 failed variants: ILP/TLP/locality/fusion/tiling all regress).
// ---------------------------------------------------------------------------
__global__ __launch_bounds__(256, 1) void qkv_mfma_kernel(
    const ushort_t* __restrict__ Xrh, const ushort_t* __restrict__ Xrl,
    const ushort_t* __restrict__ Wrh, const ushort_t* __restrict__ Wrl,
    float* __restrict__ qo, float* __restrict__ ko, float* __restrict__ vo)
{
    const int z = blockIdx.z;
    float* __restrict__ out = (z == 0) ? qo : (z == 1) ? ko : vo;
    const ushort_t* Wh = Wrh + (size_t)z * 196608;
    const ushort_t* Wl = Wrl + (size_t)z * 196608;
    const int m0 = blockIdx.y * 128;
    const int c0 = blockIdx.x * 128;
    const int hg = c0 >> 8;
    const int o0 = c0 & 255;
    const int tid  = threadIdx.x;
    const int lane = tid & 63;
    const int w    = tid >> 6;
    const int wm   = (w >> 1) * 64;
    const int wn   = (w & 1) * 64;
    const int lm   = lane & 15;
    const int lq   = lane >> 4;
    const int tA0  = (m0 + wm) >> 4;
    const int ct0  = (o0 + wn) >> 4;

    f32x4 acc[4][4];
    #pragma unroll
    for (int i = 0; i < 4; ++i)
        #pragma unroll
        for (int j = 0; j < 4; ++j) acc[i][j] = (f32x4)(0.0f);

    for (int ks = 0; ks < 24; ++ks) {
        const int g = ks >> 1;
        int gp = g - hg; if (gp < 0) gp += NG;
        bf16x8 ah[4], al[4], bh[4], bl[4];
        #pragma unroll
        for (int mt = 0; mt < 4; ++mt) {
            const size_t aoff = ((size_t)(tA0 + mt) * 96 + ks * 4 + lq) * 128 + lm * 8;
            ah[mt] = *(const bf16x8*)(Xrh + aoff);
            al[mt] = *(const bf16x8*)(Xrl + aoff);
        }
        const size_t bbase = ((size_t)(gp * 16 + ct0) * 8 + (ks & 1) * 4 + lq) * 128 + lm * 8;
        #pragma unroll
        for (int nt = 0; nt < 4; ++nt) {
            bh[nt] = *(const bf16x8*)(Wh + bbase + nt * 1024);
            bl[nt] = *(const bf16x8*)(Wl + bbase + nt * 1024);
        }
        #pragma unroll
        for (int mt = 0; mt < 4; ++mt)
            #pragma unroll
            for (int nt = 0; nt < 4; ++nt) {
                acc[mt][nt] = __builtin_amdgcn_mfma_f32_16x16x32_bf16(ah[mt], bh[nt], acc[mt][nt], 0, 0, 0);
                acc[mt][nt] = __builtin_amdgcn_mfma_f32_16x16x32_bf16(ah[mt], bl[nt], acc[mt][nt], 0, 0, 0);
                acc[mt][nt] = __builtin_amdgcn_mfma_f32_16x16x32_bf16(al[mt], bh[nt], acc[mt][nt], 0, 0, 0);
            }
    }
    #pragma unroll
    for (int mt = 0; mt < 4; ++mt)
        #pragma unroll
        for (int r = 0; r < 4; ++r) {
            float* dst = out + (size_t)(m0 + wm + mt * 16 + lq * 4 + r) * DQK + c0 + wn + lm;
            #pragma unroll
            for (int nt = 0; nt < 4; ++nt) dst[nt * 16] = acc[mt][nt][r];
        }
}

// ---------------------------------------------------------------------------
// Kernel 2: K-ONLY RMSNorm + fused ropes -> split-bf16 Kr B-fragment planes.
// Round-15: 2 THREADS PER ROW (sub = channel half; rope f-dim splits cleanly
// at f=8). Per-thread trig chain halves (9 sincos vs 17); grid 384 -> 768
// blocks = 12 waves/CU. RMS combine = one shfl_xor over adjacent lanes.
// ---------------------------------------------------------------------------
__global__ __launch_bounds__(256) void norm_rope_kernel(
    const float* __restrict__ kin,
    ushort_t* __restrict__ krh, ushort_t* __restrict__ krl,
    const float* __restrict__ coords,
    const int* __restrict__ seq,
    const float* __restrict__ kw,
    const float* __restrict__ pf)
{
    const int t2  = blockIdx.x * 256 + threadIdx.x;   // [0, 196608)
    const int hid = t2 >> 1;
    const int sub = t2 & 1;                           // channel half 0/1
    const int gh = hid % GHH;
    const int bn = hid / GHH;
    const int g = gh >> 3;
    const int h = gh & 7;
    const float* kp = kin + (size_t)hid * CQK + sub * 16;
    float xk[16];
    #pragma unroll
    for (int u = 0; u < 4; ++u) *(float4*)(xk + 4 * u) = *(const float4*)(kp + 4 * u);

    float sk = 0.f;
    #pragma unroll
    for (int c = 0; c < 16; ++c) sk = fmaf(xk[c], xk[c], sk);
    sk += __shfl_xor(sk, 1, 64);                      // pair-combine (adjacent lanes)
    const float eps = 1.1920928955078125e-07f;
    const float invk = rsqrtf(sk * (1.f / CQK) + eps);
    #pragma unroll
    for (int c = 0; c < 16; ++c) xk[c] *= invk * kw[sub * 16 + c];

    const float pos = (float)seq[bn];
    const float cx = coords[bn * 3 + 0], cy = coords[bn * 3 + 1], cz = coords[bn * 3 + 2];
    float sg, cg;
    sincosf((float)g * 0.5235987755982988f, &sg, &cg);
    const float u0 = cg * cx + sg * cy;
    const float u1 = cg * cy - sg * cx;
    const float u2 = cz;

    #pragma unroll
    for (int fl = 0; fl < 8; ++fl) {
        const int f = sub * 8 + fl;
        const float invf = exp2f(-(float)f * 0.8304820237218405f);
        const float* fr = pf + ((size_t)h * 16 + f) * 3;
        const float ang = fmaf(pos, invf, u0 * fr[0] + u1 * fr[1] + u2 * fr[2]);
        float sn, cs;
        sincosf(ang, &sn, &cs);
        float b1 = xk[2 * fl], b2 = xk[2 * fl + 1];
        xk[2 * fl]     = b1 * cs - b2 * sn;
        xk[2 * fl + 1] = b1 * sn + b2 * cs;
    }

    const int b = bn >> 9, n = bn & 511;
    const size_t kbase = (((size_t)(b * GHH + gh) * 32 + (n >> 4)) * 4) * 128 + (n & 15) * 8;
    #pragma unroll
    for (int kcl = 0; kcl < 2; ++kcl) {
        const int kc = sub * 2 + kcl;
        ushort_t h8[8] __attribute__((aligned(16)));
        ushort_t l8[8] __attribute__((aligned(16)));
        #pragma unroll
        for (int j = 0; j < 8; ++j) {
            const float x = xk[kcl * 8 + j];
            const ushort_t hb = bf16_rne(x);
            h8[j] = hb;
            l8[j] = bf16_rne(x - __uint_as_float(((unsigned)hb) << 16));
        }
        *(uint4*)(krh + kbase + kc * 128) = *(const uint4*)h8;
        *(uint4*)(krl + kbase + kc * 128) = *(const uint4*)l8;
    }
}

// ---------------------------------------------------------------------------
// Kernel 2b: V pack — fp32 V -> split-bf16 V^T B-fragment planes.
// ---------------------------------------------------------------------------
__global__ __launch_bounds__(256) void vpack_kernel(
    const float* __restrict__ v,
    ushort_t* __restrict__ vrh, ushort_t* __restrict__ vrl)
{
    const int t  = blockIdx.x * 256 + threadIdx.x;   // [0, 393216)
    const int vd = t & 31;
    const int kc = (t >> 5) & 63;
    const int bg = t >> 11;                          // [0, 192)
    const int b  = (bg >= GHH) ? 1 : 0;
    const int gh = bg - b * GHH;
    const float* src = v + (size_t)(b * 512 + kc * 8) * DQK + gh * 32 + vd;
    ushort_t h8[8] __attribute__((aligned(16)));
    ushort_t l8[8] __attribute__((aligned(16)));
    #pragma unroll
    for (int j = 0; j < 8; ++j) {
        const float x = src[j * DQK];
        const ushort_t hb = bf16_rne(x);
        h8[j] = hb;
        l8[j] = bf16_rne(x - __uint_as_float(((unsigned)hb) << 16));
    }
    const size_t dst = ((size_t)(bg * 2 + (vd >> 4)) * 64 + kc) * 128 + (vd & 15) * 8;
    *(uint4*)(vrh + dst) = *(const uint4*)h8;
    *(uint4*)(vrl + dst) = *(const uint4*)l8;
}

// ---------------------------------------------------------------------------
// Kernel 3: MFMA flash attention, NO-MAX softmax; q norm+rope in prologue;
// AO epilogue via dead-Ps LDS repack; QBLK=64 (round-14 win, 1536 blocks).
// ---------------------------------------------------------------------------
__global__ __launch_bounds__(256, 1) void attn_mfma_kernel(
    const float* __restrict__ q,
    const ushort_t* __restrict__ krh, const ushort_t* __restrict__ krl,
    const ushort_t* __restrict__ vrh, const ushort_t* __restrict__ vrl,
    ushort_t* __restrict__ aoh,     // A-frag order [m>>4][384][16][8]
    ushort_t* __restrict__ aol,
    const float* __restrict__ coords, const int* __restrict__ seq,
    const float* __restrict__ qw, const float* __restrict__ pf)
{
    __shared__ __attribute__((aligned(16))) ushort_t Ps[64][72];

    const int gh    = blockIdx.x;
    const int chunk = blockIdx.y;          // 8 chunks of 64 q-rows
    const int b     = blockIdx.z;
    const size_t headoff = (size_t)b * NN * DQK + (size_t)gh * CQK;
    const size_t kvhead = (size_t)(b * GHH + gh) * 16384;
    const int tid  = threadIdx.x;
    const int lane = tid & 63;
    const int w    = tid >> 6;
    const int lm   = lane & 15;
    const int lq   = lane >> 4;       // quad
    const int qloc = w * 16;          // wave's local q-row base (0..48)

    const int hh = gh & 7;
    float sg, cg;
    sincosf((float)(gh >> 3) * 0.5235987755982988f, &sg, &cg);
    float invf[4], fr0[4], fr1[4], fr2[4];
    #pragma unroll
    for (int u = 0; u < 4; ++u) {
        const int f = lq * 4 + u;
        invf[u] = exp2f(-(float)f * 0.8304820237218405f);
        const float* fr = pf + ((size_t)hh * 16 + f) * 3;
        fr0[u] = fr[0]; fr1[u] = fr[1]; fr2[u] = fr[2];
    }
    float qwv[8];
    *(float4*)qwv       = *(const float4*)(qw + lq * 8);
    *(float4*)(qwv + 4) = *(const float4*)(qw + lq * 8 + 4);

    const float scale = 0.17677669529663687f;  // 1/sqrt(32)
    const float eps = 1.1920928955078125e-07f;
    bf16x8 qh, ql;
    {
        const int row = chunk * 64 + qloc + lm;
        const int bn  = b * NN + row;
        const float* qp = q + headoff + (size_t)row * DQK + lq * 8;
        float4 t0 = *(const float4*)qp;
        float4 t1 = *(const float4*)(qp + 4);
        float vals[8] = {t0.x, t0.y, t0.z, t0.w, t1.x, t1.y, t1.z, t1.w};

        float ss = 0.f;
        #pragma unroll
        for (int j = 0; j < 8; ++j) ss = fmaf(vals[j], vals[j], ss);
        ss += __shfl_xor(ss, 16, 64);
        ss += __shfl_xor(ss, 32, 64);
        const float inv = rsqrtf(ss * (1.0f / 32.0f) + eps);

        const float pos = (float)seq[bn];
        const float cx = coords[bn * 3], cy = coords[bn * 3 + 1], cz = coords[bn * 3 + 2];
        const float u0 = cg * cx + sg * cy;
        const float u1 = cg * cy - sg * cx;
        const float u2 = cz;

        float o8[8];
        #pragma unroll
        for (int u = 0; u < 4; ++u) {
            const float ang = fmaf(pos, invf[u], u0 * fr0[u] + u1 * fr1[u] + u2 * fr2[u]);
            float sn, cs;
            sincosf(ang, &sn, &cs);
            const float x1 = vals[2 * u]     * inv * qwv[2 * u];
            const float x2 = vals[2 * u + 1] * inv * qwv[2 * u + 1];
            o8[2 * u]     = x1 * cs - x2 * sn;
            o8[2 * u + 1] = x1 * sn + x2 * cs;
        }

        short h8[8], l8[8];
        #pragma unroll
        for (int j = 0; j < 8; ++j) {
            float x = o8[j] * scale;
            ushort_t hb = bf16_rne(x);
            float hf = __uint_as_float(((unsigned)hb) << 16);
            h8[j] = (short)hb;
            l8[j] = (short)bf16_rne(x - hf);
        }
        qh = *(bf16x8*)h8;
        ql = *(bf16x8*)l8;
    }

    float lacc[4];
    f32x4 o[2];
    #pragma unroll
    for (int r = 0; r < 4; ++r) lacc[r] = 0.f;
    o[0] = (f32x4)(0.0f); o[1] = (f32x4)(0.0f);

    for (int j0 = 0; j0 < NN; j0 += 64) {
        // ---- S = Q K^T for 64 keys (4 n-tiles), K frags from global ----
        f32x4 sf[4];
        #pragma unroll
        for (int nt = 0; nt < 4; ++nt) {
            const size_t kb = kvhead + ((size_t)(((j0 >> 4) + nt) * 4 + lq)) * 128 + lm * 8;
            bf16x8 bh = *(const bf16x8*)(krh + kb);
            bf16x8 bl = *(const bf16x8*)(krl + kb);
            f32x4 s = (f32x4)(0.0f);
            s = __builtin_amdgcn_mfma_f32_16x16x32_bf16(qh, bh, s, 0, 0, 0);
            s = __builtin_amdgcn_mfma_f32_16x16x32_bf16(qh, bl, s, 0, 0, 0);
            s = __builtin_amdgcn_mfma_f32_16x16x32_bf16(ql, bh, s, 0, 0, 0);
            sf[nt] = s;
        }

        // ---- p = exp(s); per-lane row-sum; P (bf16) -> wave-private LDS ----
        #pragma unroll
        for (int nt = 0; nt < 4; ++nt)
            #pragma unroll
            for (int r = 0; r < 4; ++r) {
                const float p = __expf(sf[nt][r]);
                lacc[r] += p;
                Ps[qloc + lq * 4 + r][nt * 16 + lm] = bf16_rne(p);
            }

        // ---- O += P V (no barrier: Ps rows wave-private) ----
        #pragma unroll
        for (int kt = 0; kt < 2; ++kt) {
            bf16x8 pa = *(const bf16x8*)&Ps[qloc + lm][kt * 32 + lq * 8];
            #pragma unroll
            for (int vt = 0; vt < 2; ++vt) {
                const size_t vb = kvhead + ((size_t)(vt * 64 + (j0 >> 3) + kt * 4 + lq) * 16 + lm) * 8;
                bf16x8 bvh = *(const bf16x8*)(vrh + vb);
                bf16x8 bvl = *(const bf16x8*)(vrl + vb);
                o[vt] = __builtin_amdgcn_mfma_f32_16x16x32_bf16(pa, bvh, o[vt], 0, 0, 0);
                o[vt] = __builtin_amdgcn_mfma_f32_16x16x32_bf16(pa, bvl, o[vt], 0, 0, 0);
            }
        }
    }

    // ---- single end-of-kernel l reduction over the 16 col-lanes ----
    #pragma unroll
    for (int r = 0; r < 4; ++r) {
        float t = lacc[r];
        t += __shfl_xor(t, 1, 64);
        t += __shfl_xor(t, 2, 64);
        t += __shfl_xor(t, 4, 64);
        t += __shfl_xor(t, 8, 64);
        lacc[r] = 1.f / t;
    }

    // ---- epilogue: normalize + pack into dead Ps (u32 = hi<<16|lo), then
    //      drain as coalesced uint4 stores in A-FRAGMENT order ----
    __syncthreads();                               // all waves done with Ps
    unsigned int* bufU = (unsigned int*)&Ps[0][0]; // 2048 u32 = 8 KB
    const int mtbase0 = (b * 512 + chunk * 64) >> 4;
    const int kcl0 = lm >> 3;                      // 0/1 (x1 goes to +2)
    {
        const int lmt = w;                         // local mtile 0..3
        #pragma unroll
        for (int r = 0; r < 4; ++r) {
            const int i = (lq * 4 + r) * 8 + (lm & 7);
            const float x0 = o[0][r] * lacc[r];
            const float x1 = o[1][r] * lacc[r];
            const ushort_t h0 = bf16_rne(x0);
            const ushort_t h1 = bf16_rne(x1);
            const ushort_t l0 = bf16_rne(x0 - __uint_as_float(((unsigned)h0) << 16));
            const ushort_t l1 = bf16_rne(x1 - __uint_as_float(((unsigned)h1) << 16));
            bufU[(lmt * 4 + kcl0) * 128 + i]       = (((unsigned)h0) << 16) | (unsigned)l0;
            bufU[(lmt * 4 + kcl0 + 2) * 128 + i]   = (((unsigned)h1) << 16) | (unsigned)l1;
        }
    }
    __syncthreads();
    // drain: 2048 u32 -> 256 chunks of 8 elems; 256 threads x 1 chunk
    {
        const int L   = tid * 8;                   // u32 index
        const int lmt = L >> 9;                    // /512
        const int kcl = (L >> 7) & 3;
        const int i0  = L & 127;
        const unsigned int* p = bufU + L;
        const uint4 a = *(const uint4*)p;
        const uint4 c = *(const uint4*)(p + 4);
        uint4 hi4, lo4;
        hi4.x = (a.x >> 16) | (a.y & 0xffff0000u);
        hi4.y = (a.z >> 16) | (a.w & 0xffff0000u);
        hi4.z = (c.x >> 16) | (c.y & 0xffff0000u);
        hi4.w = (c.z >> 16) | (c.w & 0xffff0000u);
        lo4.x = (a.x & 0xffffu) | (a.y << 16);
        lo4.y = (a.z & 0xffffu) | (a.w << 16);
        lo4.z = (c.x & 0xffffu) | (c.y << 16);
        lo4.w = (c.z & 0xffffu) | (c.w << 16);
        const size_t gaddr = ((size_t)(mtbase0 + lmt) * 384 + (gh * 4 + kcl)) * 128 + i0;
        *(uint4*)(aoh + gaddr) = hi4;
        *(uint4*)(aol + gaddr) = lo4;
    }
}

// ---------------------------------------------------------------------------
// Kernel 4: output projection, split-bf16 MFMA, split-K=8, NO LDS/barriers.
// (split-K=4 tested round-12: regressed — parallelism beats traffic here.)
// ---------------------------------------------------------------------------
__global__ __launch_bounds__(256, 1) void oproj_mfma_kernel(
    const ushort_t* __restrict__ Arh, const ushort_t* __restrict__ Arl,
    const ushort_t* __restrict__ Worh, const ushort_t* __restrict__ Worl,
    float* __restrict__ part)                                 // [8][1024][768]
{
    const int h  = blockIdx.x;
    const int m0 = blockIdx.y * 128;
    const int kz = blockIdx.z;
    const int tid  = threadIdx.x;
    const int lane = tid & 63;
    const int w    = tid >> 6;
    const int wm   = (w >> 1) * 64;
    const int wn   = (w & 1) * 32;
    const int lm   = lane & 15;
    const int lq   = lane >> 4;
    const int tA0  = (m0 + wm) >> 4;
    const int ctb  = wn >> 4;               // 0 or 2

    f32x4 acc[4][2];
    #pragma unroll
    for (int i = 0; i < 4; ++i) { acc[i][0] = (f32x4)(0.0f); acc[i][1] = (f32x4)(0.0f); }

    for (int ks = 0; ks < 12; ++ks) {
        const int k0 = kz * 384 + ks * 32;
        const int g  = k0 >> 8;
        int gp = g - h; if (gp < 0) gp += NG;
        const int kcA = kz * 48 + ks * 4 + lq;
        const int kcB = ((k0 & 255) >> 3) + lq;
        bf16x8 ah[4], al[4], bh[2], bl[2];
        #pragma unroll
        for (int mt = 0; mt < 4; ++mt) {
            const size_t aoff = ((size_t)(tA0 + mt) * 384 + kcA) * 128 + lm * 8;
            ah[mt] = *(const bf16x8*)(Arh + aoff);
            al[mt] = *(const bf16x8*)(Arl + aoff);
        }
        const size_t bbase = ((size_t)(gp * 4 + ctb) * 32 + kcB) * 128 + lm * 8;
        #pragma unroll
        for (int nt = 0; nt < 2; ++nt) {
            bh[nt] = *(const bf16x8*)(Worh + bbase + nt * 4096);
            bl[nt] = *(const bf16x8*)(Worl + bbase + nt * 4096);
        }
        #pragma unroll
        for (int mt = 0; mt < 4; ++mt)
            #pragma unroll
            for (int nt = 0; nt < 2; ++nt) {
                acc[mt][nt] = __builtin_amdgcn_mfma_f32_16x16x32_bf16(ah[mt], bh[nt], acc[mt][nt], 0, 0, 0);
                acc[mt][nt] = __builtin_amdgcn_mfma_f32_16x16x32_bf16(ah[mt], bl[nt], acc[mt][nt], 0, 0, 0);
                acc[mt][nt] = __builtin_amdgcn_mfma_f32_16x16x32_bf16(al[mt], bh[nt], acc[mt][nt], 0, 0, 0);
            }
    }
    float* dst0 = part + (size_t)kz * (NROWS * DOUT);
    #pragma unroll
    for (int mt = 0; mt < 4; ++mt)
        #pragma unroll
        for (int r = 0; r < 4; ++r) {
            float* dst = dst0 + (size_t)(m0 + wm + mt * 16 + lq * 4 + r) * DOUT + h * 64 + wn + lm;
            dst[0]  = acc[mt][0][r];
            dst[16] = acc[mt][1][r];
        }
}

__global__ __launch_bounds__(256) void reduce8_kernel(
    const float* __restrict__ part, float* __restrict__ out)
{
    const int i = blockIdx.x * 256 + threadIdx.x;   // over 196608 float4s
    const float4* p = (const float4*)part;
    const int s = NROWS * DOUT / 4;                 // 196608
    float4 r = p[i];
    #pragma unroll
    for (int j = 1; j < 8; ++j) {
        float4 t = p[i + j * s];
        r.x += t.x; r.y += t.y; r.z += t.z; r.w += t.w;
    }
    ((float4*)out)[i] = r;
}

// ---------------------------------------------------------------------------
extern "C" void kernel_launch(void* const* d_in, const int* in_sizes, int n_in,
                              void* d_out, int out_size, void* d_ws, size_t ws_size,
                              hipStream_t stream)
{
    const float* feat   = (const float*)d_in[0];
    const float* coords = (const float*)d_in[1];
    const float* Wq     = (const float*)d_in[2];
    const float* Wk     = (const float*)d_in[3];
    const float* Wv     = (const float*)d_in[4];
    const float* Wo     = (const float*)d_in[5];
    const float* qw     = (const float*)d_in[6];
    const float* kw     = (const float*)d_in[7];
    const float* pf     = (const float*)d_in[8];
    const int*   seq    = (const int*)d_in[9];

    // regions (SZU floats each): qreg | kreg | vreg | aoreg
    float* qreg  = (float*)d_ws;
    float* kreg  = qreg + SZU;
    float* vreg  = kreg + SZU;
    float* aoreg = vreg + SZU;

    // phase 1: Xr + Wqkv planes in aoreg; WOr planes staged in d_out
    ushort_t* Xrh = (ushort_t*)aoreg;
    ushort_t* Xrl = Xrh + (size_t)NROWS * DIN;               // 786432 each
    ushort_t* Wqh = Xrl + (size_t)NROWS * DIN;
    ushort_t* Wql = Wqh + (size_t)3 * 196608;
    ushort_t* WOrh = (ushort_t*)d_out;
    ushort_t* WOrl = WOrh + (size_t)196608;
    // phase 2: qkv -> q,k,v fp32 in qreg,kreg,vreg.
    // norm_rope (k-only): k fp32 -> Kr planes -> aoreg (Xr/W dead).
    ushort_t* Krh = (ushort_t*)aoreg;
    ushort_t* Krl = Krh + SZU;
    // vpack: Vr planes -> kreg (k fp32 dead after norm_rope).
    ushort_t* Vrh = (ushort_t*)kreg;
    ushort_t* Vrl = Vrh + SZU;
    // attn: AOr planes -> vreg (v fp32 dead after vpack).
    ushort_t* AOrh = (ushort_t*)vreg;
    ushort_t* AOrl = AOrh + SZU;
    // after attn: partials [8][1024][768] = 24 MB -> qreg+kreg (contiguous).
    float*    part = (float*)d_ws;

    prep_kernel<<<dim3(768), 256, 0, stream>>>(feat, Wq, Wk, Wv, Wo,
        Xrh, Xrl, Wqh, Wql, WOrh, WOrl);
    qkv_mfma_kernel<<<dim3(24, 8, 3), 256, 0, stream>>>(Xrh, Xrl, Wqh, Wql, qreg, kreg, vreg);
    norm_rope_kernel<<<dim3(768), 256, 0, stream>>>(kreg, Krh, Krl, coords, seq, kw, pf);
    vpack_kernel<<<dim3(1536), 256, 0, stream>>>(vreg, Vrh, Vrl);
    attn_mfma_kernel<<<dim3(96, 8, 2), 256, 0, stream>>>(qreg, Krh, Krl, Vrh, Vrl, AOrh, AOrl,
                                                         coords, seq, qw, pf);
    oproj_mfma_kernel<<<dim3(12, 8, 8), 256, 0, stream>>>(AOrh, AOrl, WOrh, WOrl, part);
    reduce8_kernel<<<dim3(768), 256, 0, stream>>>(part, (float*)d_out);
}